// Round 6
// baseline (530.697 us; speedup 1.0000x reference)
//
#include <hip/hip_runtime.h>

#define NB 4
#define CHN 512
#define HWD 4096
#define LTOT (NB*HWD)
#define FEAT_ 256
#define POOL_ 8192

typedef __attribute__((ext_vector_type(8))) __bf16 bf16x8;
typedef __attribute__((ext_vector_type(8))) unsigned short u16x8;
typedef __attribute__((ext_vector_type(8))) _Float16 f16x8;
typedef __attribute__((ext_vector_type(4))) float f32x4;
typedef __attribute__((ext_vector_type(16))) float f32x16;

static __device__ __forceinline__ unsigned short f2bf(float f){
  union { float f; unsigned u; } c; c.f = f;
  unsigned u = c.u;
  u += 0x7fffu + ((u >> 16) & 1u);   // round-to-nearest-even
  return (unsigned short)(u >> 16);
}

static __device__ __forceinline__ unsigned cvt_pk(float lo, float hi){
  unsigned r;
  asm("v_cvt_pk_bf16_f32 %0, %1, %2" : "=v"(r) : "v"(lo), "v"(hi));
  return r;   // [15:0]=bf16(lo), [31:16]=bf16(hi)
}

static __device__ __forceinline__ f32x4 mfma16(bf16x8 a, bf16x8 b, f32x4 c){
  return __builtin_amdgcn_mfma_f32_16x16x32_bf16(a, b, c, 0, 0, 0);
}
static __device__ __forceinline__ f32x16 mfma32(bf16x8 a, bf16x8 b, f32x16 c){
  return __builtin_amdgcn_mfma_f32_32x32x16_bf16(a, b, c, 0, 0, 0);
}

static __device__ __forceinline__ bf16x8 ld_bf8(const void* p){
  u16x8 v = *(const u16x8*)p;
  return __builtin_bit_cast(bf16x8, v);
}

static __device__ __forceinline__ void gload16(const void* g, void* l){
  __builtin_amdgcn_global_load_lds((const __attribute__((address_space(1))) void*)g,
                                   (__attribute__((address_space(3))) void*)l, 16, 0, 0);
}

// ---------------- f32 -> bf16 convert (layout-preserving) ----------------
__global__ void k_cvt(const float* __restrict__ src, unsigned short* __restrict__ dst, int n4){
  int i = blockIdx.x * 256 + threadIdx.x;
  if (i < n4) {
    const float4 v = *(const float4*)(src + (size_t)i * 4);
    ushort4 o; o.x = f2bf(v.x); o.y = f2bf(v.y); o.z = f2bf(v.z); o.w = f2bf(v.w);
    *(ushort4*)(dst + (size_t)i * 4) = o;
  }
}

// ---------------- pool [256][8192] f32 -> poolV [256][8192] bf16 ----------------
// per-32 p-block sigma-interleave: position p' holds actual p = (p'>>1) + 16*(p'&1)
// (matches the packed-P k-order of the PV mfma32)
__global__ __launch_bounds__(256) void k_poolV(const float* __restrict__ pool,
                                               unsigned short* __restrict__ poolV){
  int t = blockIdx.x * 256 + threadIdx.x;    // 0..262143
  int iq  = t & 3;
  int blk = (t >> 2) & 255;
  int f   = t >> 10;
  const float* src = pool + (size_t)f * POOL_ + blk*32;
  float4 lo = *(const float4*)(src + iq*4);
  float4 hi = *(const float4*)(src + 16 + iq*4);
  u16x8 o;
  o[0]=f2bf(lo.x); o[1]=f2bf(hi.x); o[2]=f2bf(lo.y); o[3]=f2bf(hi.y);
  o[4]=f2bf(lo.z); o[5]=f2bf(hi.z); o[6]=f2bf(lo.w); o[7]=f2bf(hi.w);
  *(u16x8*)(poolV + (size_t)f * POOL_ + blk*32 + iq*8) = o;
}

// ---------------- pool [256][8192] f32 -> poolT_swz [8192][256] bf16 ----------------
// row p stored with byte_off(f) = (f*2) ^ ((p&7)<<4)
__global__ __launch_bounds__(256) void k_poolT(const float* __restrict__ pool,
                                               unsigned short* __restrict__ poolT){
  __shared__ float tile[32][33];
  int bf = blockIdx.x & 7;
  int bp = blockIdx.x >> 3;
  int t = threadIdx.x;
  int fi = t >> 3, j = (t & 7) * 4;
  const float4 v = *(const float4*)(pool + (size_t)(bf*32 + fi) * POOL_ + bp*32 + j);
  tile[fi][j+0] = v.x; tile[fi][j+1] = v.y; tile[fi][j+2] = v.z; tile[fi][j+3] = v.w;
  __syncthreads();
  int pi = t >> 3, fj = (t & 7) * 4;
  int p = bp*32 + pi;
  ushort4 o;
  o.x = f2bf(tile[fj+0][pi]); o.y = f2bf(tile[fj+1][pi]);
  o.z = f2bf(tile[fj+2][pi]); o.w = f2bf(tile[fj+3][pi]);
  int fbyte = (bf*32 + fj) * 2;
  char* dst = (char*)poolT + (size_t)p * 512 + (fbyte ^ ((p & 7) << 4));
  *(ushort4*)dst = o;
}

// ---------------- x [4][512][4096] f32 -> xT [4][4096][512] bf16 ----------------
__global__ __launch_bounds__(256) void k_xT(const float* __restrict__ x,
                                            unsigned short* __restrict__ xT){
  __shared__ float tile[32][33];
  int b = blockIdx.x;
  int lt = b & 127; int ct = (b >> 7) & 15; int n = b >> 11;
  int t = threadIdx.x;
  int fi = t >> 3, j = (t & 7) * 4;
  const float4 v = *(const float4*)(x + ((size_t)(n*CHN + ct*32 + fi)) * HWD + lt*32 + j);
  tile[fi][j+0] = v.x; tile[fi][j+1] = v.y; tile[fi][j+2] = v.z; tile[fi][j+3] = v.w;
  __syncthreads();
  int pi = t >> 3, fj = (t & 7) * 4;
  ushort4 o;
  o.x = f2bf(tile[fj+0][pi]); o.y = f2bf(tile[fj+1][pi]);
  o.z = f2bf(tile[fj+2][pi]); o.w = f2bf(tile[fj+3][pi]);
  *(ushort4*)((char*)xT + ((size_t)(n*HWD + lt*32 + pi)) * 1024 + (ct*32 + fj) * 2) = o;
}

// ---------------- theta GEMM: Q[l][f] = sum_c xT[l][c] * wt[f][c] ----------------
__global__ __launch_bounds__(256) void k_theta(const unsigned short* __restrict__ xT,
                                               const unsigned short* __restrict__ wt,
                                               unsigned short* __restrict__ Q){
  int w = threadIdx.x >> 6, lane = threadIdx.x & 63;
  int lq = lane & 15, hq = lane >> 4;
  int lbase = blockIdx.x * 64 + w * 16;
  const char* xb = (const char*)xT;
  const char* wb = (const char*)wt;
  f32x4 acc[16];
  #pragma unroll
  for (int i = 0; i < 16; ++i) acc[i] = {};
  #pragma unroll 2
  for (int kk = 0; kk < 16; ++kk) {
    bf16x8 a = ld_bf8(xb + (size_t)(lbase + lq) * 1024 + kk*64 + hq*16);
    #pragma unroll
    for (int fi = 0; fi < 16; ++fi) {
      bf16x8 bfr = ld_bf8(wb + (size_t)(fi*16 + lq) * 1024 + kk*64 + hq*16);
      acc[fi] = mfma16(a, bfr, acc[fi]);
    }
  }
  #pragma unroll
  for (int fi = 0; fi < 16; ++fi) {
    #pragma unroll
    for (int r = 0; r < 4; ++r) {
      int l = lbase + hq*4 + r;
      Q[(size_t)l * 256 + fi*16 + lq] = f2bf(acc[fi][r]);
    }
  }
}

// ---------------- fused flash attention over the concept pool ----------------
// Grid 1024 = 256 q-blocks x 4 slices; block 128 thr (2 waves x 32 q-rows).
// R5 skeleton (single-buffer staging, 4 blocks/CU) with: packed-interleaved
// bf16 P via v_cvt_pk_bf16_f32, PV as mfma_32x32x16 (P direct A-operand),
// defer-max THR=8, V granule XOR-swizzle (both-sides).
__global__ __launch_bounds__(128, 2) void k_attn(const unsigned short* __restrict__ Qg,
                                                 const unsigned short* __restrict__ poolT,
                                                 const unsigned short* __restrict__ poolV,
                                                 _Float16* __restrict__ accP,
                                                 float* __restrict__ pm,
                                                 float* __restrict__ ps){
  __shared__ __attribute__((aligned(16))) unsigned short K_lds[32*256];   // 16 KB
  __shared__ __attribute__((aligned(16))) unsigned short V_lds[8192];     // 16 KB (swizzled granules)
  __shared__ __attribute__((aligned(16))) unsigned short P_lds[2][32][40];//  5 KB
  __shared__ float Sc[2][32];
  __shared__ float As[2][32];

  int w = threadIdx.x >> 6, lane = threadIdx.x & 63;
  int lq = lane & 15, hq = lane >> 4;
  int ln = lane & 31, h2 = lane >> 5;
  int qblock = blockIdx.x & 255, slice = blockIdx.x >> 8;
  int qa0 = qblock * 64 + w * 32;

  const char* qp = (const char*)Qg;
  bf16x8 qfa[8], qfb[8];
  #pragma unroll
  for (int kk = 0; kk < 8; ++kk) {
    qfa[kk] = ld_bf8(qp + (size_t)(qa0 + lq) * 512 + kk*64 + hq*16);
    qfb[kk] = ld_bf8(qp + (size_t)(qa0 + 16 + lq) * 512 + kk*64 + hq*16);
  }

  f32x16 acc32[8];
  #pragma unroll
  for (int i = 0; i < 8; ++i) acc32[i] = {};
  f32x4 accsA = {}, accsB = {};
  float ma0 = -__builtin_inff(), ma1 = -__builtin_inff(),
        ma2 = -__builtin_inff(), ma3 = -__builtin_inff();
  float mb0 = -__builtin_inff(), mb1 = -__builtin_inff(),
        mb2 = -__builtin_inff(), mb3 = -__builtin_inff();
  u16x8 ov;
  #pragma unroll
  for (int i = 0; i < 8; ++i) ov[i] = 0x3F80;   // bf16 1.0
  const bf16x8 ONES = __builtin_bit_cast(bf16x8, ov);

  const char* ktb = (const char*)poolT;
  const char* vnb = (const char*)poolV;
  // V staging: gload chunk cw writes LDS bytes [cw*1024 + lane*16]; the LDS
  // granule there represents (pc=cw>>2, f) with f = y ^ ((y>>3)&7) (inverse of
  // the read-side swizzle), y = (cw&3)*64 + lane.
  size_t vsrcl[8]; int vdst[8];
  #pragma unroll
  for (int i = 0; i < 8; ++i) {
    int cw = 2*i + w;
    int pc = cw >> 2;
    int y  = (cw & 3) * 64 + lane;
    int fs = y ^ ((y >> 3) & 7);
    vdst[i] = cw * 1024;
    vsrcl[i] = (size_t)fs * 16384 + (size_t)pc * 16;
  }
  int xorv = (lq & 7) << 3;
  unsigned short (*Pw)[40] = P_lds[w];

  for (int t = 0; t < 64; ++t) {
    int tt = slice * 64 + t;
    __syncthreads();                    // all waves done reading previous tile
    #pragma unroll
    for (int i = 0; i < 8; ++i)
      gload16(ktb + (size_t)tt*16384 + (w*8 + i)*1024 + lane*16,
              (char*)K_lds + (w*8 + i)*1024);
    #pragma unroll
    for (int i = 0; i < 8; ++i)
      gload16(vnb + vsrcl[i] + (size_t)tt*64, (char*)V_lds + vdst[i]);
    __syncthreads();                    // drains vmcnt(0), then barrier

    // S = Q @ K^T : two q-groups x 32 p (UNCHANGED from R5)
    f32x4 s0a = {}, s1a = {}, s0b = {}, s1b = {};
    #pragma unroll
    for (int kk = 0; kk < 8; ++kk) {
      int co = (kk*32 + hq*8) ^ xorv;
      bf16x8 k0 = ld_bf8(&K_lds[lq*256 + co]);
      bf16x8 k1 = ld_bf8(&K_lds[(16 + lq)*256 + co]);
      s0a = mfma16(qfa[kk], k0, s0a);
      s1a = mfma16(qfa[kk], k1, s1a);
      s0b = mfma16(qfb[kk], k0, s0b);
      s1b = mfma16(qfb[kk], k1, s1b);
    }

    // defer-max online softmax: rescale only when max grows by > 8
    float pa0 = fmaxf(s0a[0], s1a[0]), pa1 = fmaxf(s0a[1], s1a[1]),
          pa2 = fmaxf(s0a[2], s1a[2]), pa3 = fmaxf(s0a[3], s1a[3]);
    float pb0 = fmaxf(s0b[0], s1b[0]), pb1 = fmaxf(s0b[1], s1b[1]),
          pb2 = fmaxf(s0b[2], s1b[2]), pb3 = fmaxf(s0b[3], s1b[3]);
    bool ex = (pa0 > ma0+8.f) | (pa1 > ma1+8.f) | (pa2 > ma2+8.f) | (pa3 > ma3+8.f) |
              (pb0 > mb0+8.f) | (pb1 > mb1+8.f) | (pb2 > mb2+8.f) | (pb3 > mb3+8.f);
    if (__any((int)ex)) {
      #pragma unroll
      for (int msk = 1; msk < 16; msk <<= 1) {
        pa0 = fmaxf(pa0, __shfl_xor(pa0, msk));
        pa1 = fmaxf(pa1, __shfl_xor(pa1, msk));
        pa2 = fmaxf(pa2, __shfl_xor(pa2, msk));
        pa3 = fmaxf(pa3, __shfl_xor(pa3, msk));
        pb0 = fmaxf(pb0, __shfl_xor(pb0, msk));
        pb1 = fmaxf(pb1, __shfl_xor(pb1, msk));
        pb2 = fmaxf(pb2, __shfl_xor(pb2, msk));
        pb3 = fmaxf(pb3, __shfl_xor(pb3, msk));
      }
      float na0 = fmaxf(ma0, pa0), na1 = fmaxf(ma1, pa1),
            na2 = fmaxf(ma2, pa2), na3 = fmaxf(ma3, pa3);
      float nb0 = fmaxf(mb0, pb0), nb1 = fmaxf(mb1, pb1),
            nb2 = fmaxf(mb2, pb2), nb3 = fmaxf(mb3, pb3);
      float sa0 = __expf(ma0 - na0), sa1 = __expf(ma1 - na1),
            sa2 = __expf(ma2 - na2), sa3 = __expf(ma3 - na3);
      float sb0 = __expf(mb0 - nb0), sb1 = __expf(mb1 - nb1),
            sb2 = __expf(mb2 - nb2), sb3 = __expf(mb3 - nb3);
      ma0 = na0; ma1 = na1; ma2 = na2; ma3 = na3;
      mb0 = nb0; mb1 = nb1; mb2 = nb2; mb3 = nb3;
      accsA[0] *= sa0; accsA[1] *= sa1; accsA[2] *= sa2; accsA[3] *= sa3;
      accsB[0] *= sb0; accsB[1] *= sb1; accsB[2] *= sb2; accsB[3] *= sb3;
      // broadcast per-q scale (q-local rows: a = 4hq+r, b = 16+4hq+r)
      if (lq == 0) {
        Sc[w][4*hq+0] = sa0; Sc[w][4*hq+1] = sa1;
        Sc[w][4*hq+2] = sa2; Sc[w][4*hq+3] = sa3;
        Sc[w][16+4*hq+0] = sb0; Sc[w][16+4*hq+1] = sb1;
        Sc[w][16+4*hq+2] = sb2; Sc[w][16+4*hq+3] = sb3;
      }
      f32x4 s4[4];
      #pragma unroll
      for (int blk = 0; blk < 4; ++blk)
        s4[blk] = *(const f32x4*)&Sc[w][8*blk + 4*h2];
      #pragma unroll
      for (int fb = 0; fb < 8; ++fb)
        #pragma unroll
        for (int r = 0; r < 16; ++r)
          acc32[fb][r] *= s4[r>>2][r&3];
    }

    // P = exp(S - m) packed-interleaved bf16: u32 holds (p=lq, p=16+lq)
    {
      int q0 = hq * 4;
      *(unsigned*)&Pw[q0+0][lq*2] = cvt_pk(__expf(s0a[0]-ma0), __expf(s1a[0]-ma0));
      *(unsigned*)&Pw[q0+1][lq*2] = cvt_pk(__expf(s0a[1]-ma1), __expf(s1a[1]-ma1));
      *(unsigned*)&Pw[q0+2][lq*2] = cvt_pk(__expf(s0a[2]-ma2), __expf(s1a[2]-ma2));
      *(unsigned*)&Pw[q0+3][lq*2] = cvt_pk(__expf(s0a[3]-ma3), __expf(s1a[3]-ma3));
      *(unsigned*)&Pw[16+q0+0][lq*2] = cvt_pk(__expf(s0b[0]-mb0), __expf(s1b[0]-mb0));
      *(unsigned*)&Pw[16+q0+1][lq*2] = cvt_pk(__expf(s0b[1]-mb1), __expf(s1b[1]-mb1));
      *(unsigned*)&Pw[16+q0+2][lq*2] = cvt_pk(__expf(s0b[2]-mb2), __expf(s1b[2]-mb2));
      *(unsigned*)&Pw[16+q0+3][lq*2] = cvt_pk(__expf(s0b[3]-mb3), __expf(s1b[3]-mb3));
    }

    // row-sums via ones-MFMA (k-order irrelevant)
    bf16x8 paA = ld_bf8(&Pw[lq][hq*8]);
    bf16x8 paB = ld_bf8(&Pw[16+lq][hq*8]);
    accsA = mfma16(paA, ONES, accsA);
    accsB = mfma16(paB, ONES, accsB);

    // PV via mfma 32x32x16: A = P rows (q=lane&31), B = swizzled V granules
    #pragma unroll
    for (int ph = 0; ph < 2; ++ph) {
      bf16x8 pfrag = ld_bf8(&Pw[ln][ph*16 + h2*8]);
      #pragma unroll
      for (int fb = 0; fb < 8; ++fb) {
        int f = fb*32 + ln;
        int swz = ((fb*4 + (ln>>3)) & 7) << 4;
        bf16x8 vfrag = ld_bf8((char*)V_lds + (ph*2 + h2)*4096 + ((f*16) ^ swz));
        acc32[fb] = mfma32(pfrag, vfrag, acc32[fb]);
      }
    }
  }

  // ---- epilogue: per-slice normalized output (f16) + (m, rowsum) ----
  if (lq == 0) {
    As[w][4*hq+0] = accsA[0]; As[w][4*hq+1] = accsA[1];
    As[w][4*hq+2] = accsA[2]; As[w][4*hq+3] = accsA[3];
    As[w][16+4*hq+0] = accsB[0]; As[w][16+4*hq+1] = accsB[1];
    As[w][16+4*hq+2] = accsB[2]; As[w][16+4*hq+3] = accsB[3];
  }
  float inv[16];
  #pragma unroll
  for (int blk = 0; blk < 4; ++blk) {
    f32x4 a4 = *(const f32x4*)&As[w][8*blk + 4*h2];
    inv[blk*4+0] = 1.0f / a4[0]; inv[blk*4+1] = 1.0f / a4[1];
    inv[blk*4+2] = 1.0f / a4[2]; inv[blk*4+3] = 1.0f / a4[3];
  }
  size_t sbase = (size_t)slice * 16384 + qa0;
  #pragma unroll
  for (int fb = 0; fb < 8; ++fb) {
    #pragma unroll
    for (int r = 0; r < 16; ++r) {
      int q = (r & 3) + 8*(r >> 2) + 4*h2;
      accP[(sbase + q) * 256 + fb*32 + ln] = (_Float16)(acc32[fb][r] * inv[r]);
    }
  }
  if (lq == 0) {
    pm[sbase + 4*hq + 0] = ma0; ps[sbase + 4*hq + 0] = accsA[0];
    pm[sbase + 4*hq + 1] = ma1; ps[sbase + 4*hq + 1] = accsA[1];
    pm[sbase + 4*hq + 2] = ma2; ps[sbase + 4*hq + 2] = accsA[2];
    pm[sbase + 4*hq + 3] = ma3; ps[sbase + 4*hq + 3] = accsA[3];
    pm[sbase + 16 + 4*hq + 0] = mb0; ps[sbase + 16 + 4*hq + 0] = accsB[0];
    pm[sbase + 16 + 4*hq + 1] = mb1; ps[sbase + 16 + 4*hq + 1] = accsB[1];
    pm[sbase + 16 + 4*hq + 2] = mb2; ps[sbase + 16 + 4*hq + 2] = accsB[2];
    pm[sbase + 16 + 4*hq + 3] = mb3; ps[sbase + 16 + 4*hq + 3] = accsB[3];
  }
}

// ---------------- combine the 4 pool-slice partials (pre-normalized) ----------------
__global__ __launch_bounds__(256) void k_comb(const _Float16* __restrict__ accP,
                                              const float* __restrict__ pm,
                                              const float* __restrict__ ps,
                                              unsigned short* __restrict__ agg){
  int q = blockIdx.x * 16 + (threadIdx.x >> 4);
  int f0 = (threadIdx.x & 15) * 16;
  float m0 = pm[q], m1 = pm[16384 + q], m2 = pm[2*16384 + q], m3 = pm[3*16384 + q];
  float M = fmaxf(fmaxf(m0, m1), fmaxf(m2, m3));
  float w0 = __expf(m0 - M) * ps[q];
  float w1 = __expf(m1 - M) * ps[16384 + q];
  float w2 = __expf(m2 - M) * ps[2*16384 + q];
  float w3 = __expf(m3 - M) * ps[3*16384 + q];
  float inv = 1.0f / (w0 + w1 + w2 + w3);
  w0 *= inv; w1 *= inv; w2 *= inv; w3 *= inv;
  const _Float16* a0 = accP + (size_t)q * 256 + f0;
  #pragma unroll
  for (int j = 0; j < 16; j += 8) {
    f16x8 v0 = *(const f16x8*)(a0 + j);
    f16x8 v1 = *(const f16x8*)(a0 + j + (size_t)16384*256);
    f16x8 v2 = *(const f16x8*)(a0 + j + (size_t)2*16384*256);
    f16x8 v3 = *(const f16x8*)(a0 + j + (size_t)3*16384*256);
    u16x8 o;
    #pragma unroll
    for (int k = 0; k < 8; ++k) {
      float s = w0*(float)v0[k] + w1*(float)v1[k] + w2*(float)v2[k] + w3*(float)v3[k];
      o[k] = f2bf(s);
    }
    *(u16x8*)(agg + (size_t)q * 256 + f0 + j) = o;
  }
}

// ---------------- output GEMM + gated residual ----------------
__global__ __launch_bounds__(256) void k_out(const float* __restrict__ x,
                                             const unsigned short* __restrict__ wo,
                                             const unsigned short* __restrict__ agg,
                                             const float* __restrict__ gammap,
                                             float* __restrict__ out){
  int w = threadIdx.x >> 6, lane = threadIdx.x & 63;
  int lq = lane & 15, hq = lane >> 4;
  int b = blockIdx.x;
  int lg = b & 63, cg = (b >> 6) & 7, n = b >> 9;
  const char* wb = (const char*)wo;
  const char* ab = (const char*)agg;
  f32x4 acc[4];
  #pragma unroll
  for (int i = 0; i < 4; ++i) acc[i] = {};
  int crow = cg*64 + w*16 + lq;
  #pragma unroll
  for (int kk = 0; kk < 8; ++kk) {
    bf16x8 a = ld_bf8(wb + (size_t)crow * 512 + kk*64 + hq*16);
    #pragma unroll
    for (int li = 0; li < 4; ++li) {
      bf16x8 bb = ld_bf8(ab + (size_t)(n*HWD + lg*64 + li*16 + lq) * 512 + kk*64 + hq*16);
      acc[li] = mfma16(a, bb, acc[li]);
    }
  }
  float g = gammap[0];
  #pragma unroll
  for (int li = 0; li < 4; ++li) {
    #pragma unroll
    for (int r = 0; r < 4; ++r) {
      int c = cg*64 + w*16 + hq*4 + r;
      int l = lg*64 + li*16 + lq;
      size_t idx = ((size_t)(n*CHN + c)) * HWD + l;
      out[idx] = x[idx] + g * acc[li][r];
    }
  }
}

extern "C" void kernel_launch(void* const* d_in, const int* in_sizes, int n_in,
                              void* d_out, int out_size, void* d_ws, size_t ws_size,
                              hipStream_t stream) {
  const float* x     = (const float*)d_in[0];
  const float* wt    = (const float*)d_in[1];
  const float* wo    = (const float*)d_in[2];
  const float* pool  = (const float*)d_in[3];
  const float* gamma = (const float*)d_in[4];
  char* ws = (char*)d_ws;
  unsigned short* wt_b  = (unsigned short*)(ws + 0);         // 256 KB
  unsigned short* wo_b  = (unsigned short*)(ws + 262144);    // 256 KB
  unsigned short* poolV = (unsigned short*)(ws + 524288);    // 4 MB (sigma-interleaved)
  unsigned short* poolT = (unsigned short*)(ws + 4718592);   // 4 MB (XOR-swizzled)
  unsigned short* Qb    = (unsigned short*)(ws + 8912896);   // 8 MB
  unsigned short* aggb  = (unsigned short*)(ws + 17301504);  // 8 MB
  unsigned short* xT    = (unsigned short*)(ws + 25690112);  // 16 MB (dead after k_theta)
  _Float16*       accP  = (_Float16*)(ws + 25690112);        // 32 MB (overlaps dead xT)
  float*          pm    = (float*)(ws + 59244544);           // 256 KB
  float*          ps    = (float*)(ws + 59506688);           // 256 KB
  float* out = (float*)d_out;

  k_cvt<<<dim3(128), dim3(256), 0, stream>>>(wt, wt_b, 32768);
  k_cvt<<<dim3(128), dim3(256), 0, stream>>>(wo, wo_b, 32768);
  k_poolV<<<dim3(1024), dim3(256), 0, stream>>>(pool, poolV);
  k_poolT<<<dim3(2048), dim3(256), 0, stream>>>(pool, poolT);
  k_xT<<<dim3(8192), dim3(256), 0, stream>>>(x, xT);
  k_theta<<<dim3(256), dim3(256), 0, stream>>>(xT, wt_b, Qb);
  k_attn<<<dim3(1024), dim3(128), 0, stream>>>(Qb, poolT, poolV, accP, pm, ps);
  k_comb<<<dim3(1024), dim3(256), 0, stream>>>(accP, pm, ps, aggb);
  k_out<<<dim3(2048), dim3(256), 0, stream>>>(x, wo_b, aggb, gamma, out);
}

// Round 9
// 377.758 us; speedup vs baseline: 1.4049x; 1.4049x over previous
//
#include <hip/hip_runtime.h>

#define NB 4
#define CHN 512
#define HWD 4096
#define LTOT (NB*HWD)
#define FEAT_ 256
#define POOL_ 8192

typedef __attribute__((ext_vector_type(8))) __bf16 bf16x8;
typedef __attribute__((ext_vector_type(8))) unsigned short u16x8;
typedef __attribute__((ext_vector_type(8))) _Float16 f16x8;
typedef __attribute__((ext_vector_type(4))) float f32x4;
typedef __attribute__((ext_vector_type(16))) float f32x16;

static __device__ __forceinline__ unsigned short f2bf(float f){
  union { float f; unsigned u; } c; c.f = f;
  unsigned u = c.u;
  u += 0x7fffu + ((u >> 16) & 1u);   // round-to-nearest-even
  return (unsigned short)(u >> 16);
}

static __device__ __forceinline__ unsigned pk_f16(float lo, float hi){
  auto r = __builtin_amdgcn_cvt_pkrtz(lo, hi);   // __fp16 ext_vector(2)
  return __builtin_bit_cast(unsigned, r);        // [15:0]=f16(lo), [31:16]=f16(hi)
}

static __device__ __forceinline__ f32x4 mfma16(bf16x8 a, bf16x8 b, f32x4 c){
  return __builtin_amdgcn_mfma_f32_16x16x32_bf16(a, b, c, 0, 0, 0);
}
static __device__ __forceinline__ f32x4 mfma16h(f16x8 a, f16x8 b, f32x4 c){
  return __builtin_amdgcn_mfma_f32_16x16x32_f16(a, b, c, 0, 0, 0);
}
static __device__ __forceinline__ f32x16 mfma32h(f16x8 a, f16x8 b, f32x16 c){
  return __builtin_amdgcn_mfma_f32_32x32x16_f16(a, b, c, 0, 0, 0);
}

static __device__ __forceinline__ bf16x8 ld_bf8(const void* p){
  u16x8 v = *(const u16x8*)p;
  return __builtin_bit_cast(bf16x8, v);
}
static __device__ __forceinline__ f16x8 ld_f8(const void* p){
  u16x8 v = *(const u16x8*)p;
  return __builtin_bit_cast(f16x8, v);
}

static __device__ __forceinline__ void gload16(const void* g, void* l){
  __builtin_amdgcn_global_load_lds((const __attribute__((address_space(1))) void*)g,
                                   (__attribute__((address_space(3))) void*)l, 16, 0, 0);
}

// ---------------- f32 -> bf16 convert (layout-preserving) ----------------
__global__ void k_cvt(const float* __restrict__ src, unsigned short* __restrict__ dst, int n4){
  int i = blockIdx.x * 256 + threadIdx.x;
  if (i < n4) {
    const float4 v = *(const float4*)(src + (size_t)i * 4);
    ushort4 o; o.x = f2bf(v.x); o.y = f2bf(v.y); o.z = f2bf(v.z); o.w = f2bf(v.w);
    *(ushort4*)(dst + (size_t)i * 4) = o;
  }
}

// ---------------- pool [256][8192] f32 -> poolV [256][8192] f16 ----------------
// per-32 p-block sigma-interleave: position p' holds actual p = (p'>>1) + 16*(p'&1)
__global__ __launch_bounds__(256) void k_poolV(const float* __restrict__ pool,
                                               _Float16* __restrict__ poolV){
  int t = blockIdx.x * 256 + threadIdx.x;    // 0..262143
  int iq  = t & 3;
  int blk = (t >> 2) & 255;
  int f   = t >> 10;
  const float* src = pool + (size_t)f * POOL_ + blk*32;
  float4 lo = *(const float4*)(src + iq*4);
  float4 hi = *(const float4*)(src + 16 + iq*4);
  f16x8 o;
  o[0]=(_Float16)lo.x; o[1]=(_Float16)hi.x; o[2]=(_Float16)lo.y; o[3]=(_Float16)hi.y;
  o[4]=(_Float16)lo.z; o[5]=(_Float16)hi.z; o[6]=(_Float16)lo.w; o[7]=(_Float16)hi.w;
  *(f16x8*)(poolV + (size_t)f * POOL_ + blk*32 + iq*8) = o;
}

// ---------------- pool [256][8192] f32 -> poolT_swz [8192][256] bf16 ----------------
// row p stored with byte_off(f) = (f*2) ^ ((p&7)<<4)
__global__ __launch_bounds__(256) void k_poolT(const float* __restrict__ pool,
                                               unsigned short* __restrict__ poolT){
  __shared__ float tile[32][33];
  int bf = blockIdx.x & 7;
  int bp = blockIdx.x >> 3;
  int t = threadIdx.x;
  int fi = t >> 3, j = (t & 7) * 4;
  const float4 v = *(const float4*)(pool + (size_t)(bf*32 + fi) * POOL_ + bp*32 + j);
  tile[fi][j+0] = v.x; tile[fi][j+1] = v.y; tile[fi][j+2] = v.z; tile[fi][j+3] = v.w;
  __syncthreads();
  int pi = t >> 3, fj = (t & 7) * 4;
  int p = bp*32 + pi;
  ushort4 o;
  o.x = f2bf(tile[fj+0][pi]); o.y = f2bf(tile[fj+1][pi]);
  o.z = f2bf(tile[fj+2][pi]); o.w = f2bf(tile[fj+3][pi]);
  int fbyte = (bf*32 + fj) * 2;
  char* dst = (char*)poolT + (size_t)p * 512 + (fbyte ^ ((p & 7) << 4));
  *(ushort4*)dst = o;
}

// ---------------- x [4][512][4096] f32 -> xT [4][4096][512] bf16 ----------------
__global__ __launch_bounds__(256) void k_xT(const float* __restrict__ x,
                                            unsigned short* __restrict__ xT){
  __shared__ float tile[32][33];
  int b = blockIdx.x;
  int lt = b & 127; int ct = (b >> 7) & 15; int n = b >> 11;
  int t = threadIdx.x;
  int fi = t >> 3, j = (t & 7) * 4;
  const float4 v = *(const float4*)(x + ((size_t)(n*CHN + ct*32 + fi)) * HWD + lt*32 + j);
  tile[fi][j+0] = v.x; tile[fi][j+1] = v.y; tile[fi][j+2] = v.z; tile[fi][j+3] = v.w;
  __syncthreads();
  int pi = t >> 3, fj = (t & 7) * 4;
  ushort4 o;
  o.x = f2bf(tile[fj+0][pi]); o.y = f2bf(tile[fj+1][pi]);
  o.z = f2bf(tile[fj+2][pi]); o.w = f2bf(tile[fj+3][pi]);
  *(ushort4*)((char*)xT + ((size_t)(n*HWD + lt*32 + pi)) * 1024 + (ct*32 + fj) * 2) = o;
}

// ---------------- theta GEMM: Q[l][f] = sum_c xT[l][c] * wt[f][c] ----------------
__global__ __launch_bounds__(256) void k_theta(const unsigned short* __restrict__ xT,
                                               const unsigned short* __restrict__ wt,
                                               unsigned short* __restrict__ Q){
  int w = threadIdx.x >> 6, lane = threadIdx.x & 63;
  int lq = lane & 15, hq = lane >> 4;
  int lbase = blockIdx.x * 64 + w * 16;
  const char* xb = (const char*)xT;
  const char* wb = (const char*)wt;
  f32x4 acc[16];
  #pragma unroll
  for (int i = 0; i < 16; ++i) acc[i] = {};
  #pragma unroll 2
  for (int kk = 0; kk < 16; ++kk) {
    bf16x8 a = ld_bf8(xb + (size_t)(lbase + lq) * 1024 + kk*64 + hq*16);
    #pragma unroll
    for (int fi = 0; fi < 16; ++fi) {
      bf16x8 bfr = ld_bf8(wb + (size_t)(fi*16 + lq) * 1024 + kk*64 + hq*16);
      acc[fi] = mfma16(a, bfr, acc[fi]);
    }
  }
  #pragma unroll
  for (int fi = 0; fi < 16; ++fi) {
    #pragma unroll
    for (int r = 0; r < 4; ++r) {
      int l = lbase + hq*4 + r;
      Q[(size_t)l * 256 + fi*16 + lq] = f2bf(acc[fi][r]);
    }
  }
}

// ---------------- fused flash attention over the concept pool ----------------
// Grid 512 = 128 q-blocks x 4 slices; block 256 thr = 4 waves x 32 q-rows.
// Verified 2-phase pipeline (T3-minimum): STAGE(t+1) -> compute(t) ->
// __syncthreads() (its vmcnt(0)+lgkmcnt(0)+barrier is exactly the recipe's
// per-tile drain). Prefetch latency hides under compute; no raw barriers,
// no counted vmcnt, no setprio (null on 2-phase). K/V double-buffered;
// PV path in f16 (P via cvt_pkrtz, V f16) for precision margin.
__global__ __launch_bounds__(256, 2) void k_attn(const unsigned short* __restrict__ Qg,
                                                 const unsigned short* __restrict__ poolT,
                                                 const _Float16* __restrict__ poolV,
                                                 _Float16* __restrict__ accP,
                                                 float* __restrict__ pm,
                                                 float* __restrict__ ps){
  __shared__ __attribute__((aligned(16))) unsigned short K_lds[2][32*256]; // 32 KB
  __shared__ __attribute__((aligned(16))) _Float16 V_lds[2][8192];         // 32 KB
  __shared__ __attribute__((aligned(16))) _Float16 P_lds[4][32][40];       // 10 KB
  __shared__ float Sc[4][32];
  __shared__ float As[4][32];

  int w = threadIdx.x >> 6, lane = threadIdx.x & 63;
  int lq = lane & 15, hq = lane >> 4;
  int ln = lane & 31, h2 = lane >> 5;
  int qblock = blockIdx.x & 127, slice = blockIdx.x >> 7;
  int qa0 = qblock * 128 + w * 32;

  const char* qp = (const char*)Qg;
  bf16x8 qfa[8], qfb[8];
  #pragma unroll
  for (int kk = 0; kk < 8; ++kk) {
    qfa[kk] = ld_bf8(qp + (size_t)(qa0 + lq) * 512 + kk*64 + hq*16);
    qfb[kk] = ld_bf8(qp + (size_t)(qa0 + 16 + lq) * 512 + kk*64 + hq*16);
  }

  f32x16 acc32[8];
  #pragma unroll
  for (int i = 0; i < 8; ++i) acc32[i] = {};
  f32x4 accsA = {}, accsB = {};
  float ma0 = -__builtin_inff(), ma1 = -__builtin_inff(),
        ma2 = -__builtin_inff(), ma3 = -__builtin_inff();
  float mb0 = -__builtin_inff(), mb1 = -__builtin_inff(),
        mb2 = -__builtin_inff(), mb3 = -__builtin_inff();
  u16x8 ov;
  #pragma unroll
  for (int i = 0; i < 8; ++i) ov[i] = 0x3C00;   // f16 1.0
  const f16x8 ONESH = __builtin_bit_cast(f16x8, ov);

  const char* ktb = (const char*)poolT;
  const char* vnb = (const char*)poolV;
  // staging split 4 ways: each wave stages 4 K-chunks + 4 V-chunks (1 KB each)
  int kds[4]; size_t ksrc[4];
  int vds[4]; size_t vsrcl[4];
  #pragma unroll
  for (int i = 0; i < 4; ++i) {
    int ck = w*4 + i;
    kds[i] = ck * 1024;
    ksrc[i] = (size_t)ck * 1024 + (size_t)lane * 16;
    int pc = ck >> 2;
    int y  = (ck & 3) * 64 + lane;
    int fs = y ^ ((y >> 3) & 7);          // inverse of read-side V swizzle
    vds[i] = ck * 1024;
    vsrcl[i] = (size_t)fs * 16384 + (size_t)pc * 16;
  }
  int xorv = (lq & 7) << 3;
  _Float16 (*Pw)[40] = P_lds[w];

  // prologue: stage tile 0 into buffer 0, full drain via __syncthreads
  {
    size_t tb = (size_t)(slice * 64) * 16384;
    #pragma unroll
    for (int i = 0; i < 4; ++i) gload16(ktb + tb + ksrc[i], (char*)K_lds[0] + kds[i]);
    #pragma unroll
    for (int i = 0; i < 4; ++i) gload16(vnb + vsrcl[i] + (size_t)(slice*64)*64,
                                        (char*)V_lds[0] + vds[i]);
  }
  __syncthreads();

  int cur = 0;
  for (int t = 0; t < 64; ++t) {
    // STAGE(t+1) into buf cur^1 (last read at t-1, sealed by the barrier)
    if (t < 63) {
      size_t tb = (size_t)(slice*64 + t + 1) * 16384;
      #pragma unroll
      for (int i = 0; i < 4; ++i) gload16(ktb + tb + ksrc[i], (char*)K_lds[cur^1] + kds[i]);
      #pragma unroll
      for (int i = 0; i < 4; ++i) gload16(vnb + vsrcl[i] + (size_t)(slice*64 + t + 1)*64,
                                          (char*)V_lds[cur^1] + vds[i]);
    }

    const unsigned short* Kl = K_lds[cur];
    const char* Vl = (const char*)V_lds[cur];

    // S = Q @ K^T : two q-groups x 32 p
    f32x4 s0a = {}, s1a = {}, s0b = {}, s1b = {};
    #pragma unroll
    for (int kk = 0; kk < 8; ++kk) {
      int co = (kk*32 + hq*8) ^ xorv;
      bf16x8 k0 = ld_bf8(&Kl[lq*256 + co]);
      bf16x8 k1 = ld_bf8(&Kl[(16 + lq)*256 + co]);
      s0a = mfma16(qfa[kk], k0, s0a);
      s1a = mfma16(qfa[kk], k1, s1a);
      s0b = mfma16(qfb[kk], k0, s0b);
      s1b = mfma16(qfb[kk], k1, s1b);
    }

    // defer-max online softmax: rescale only when max grows by > 4
    float pa0 = fmaxf(s0a[0], s1a[0]), pa1 = fmaxf(s0a[1], s1a[1]),
          pa2 = fmaxf(s0a[2], s1a[2]), pa3 = fmaxf(s0a[3], s1a[3]);
    float pb0 = fmaxf(s0b[0], s1b[0]), pb1 = fmaxf(s0b[1], s1b[1]),
          pb2 = fmaxf(s0b[2], s1b[2]), pb3 = fmaxf(s0b[3], s1b[3]);
    bool ex = (pa0 > ma0+4.f) | (pa1 > ma1+4.f) | (pa2 > ma2+4.f) | (pa3 > ma3+4.f) |
              (pb0 > mb0+4.f) | (pb1 > mb1+4.f) | (pb2 > mb2+4.f) | (pb3 > mb3+4.f);
    if (__any((int)ex)) {
      #pragma unroll
      for (int msk = 1; msk < 16; msk <<= 1) {
        pa0 = fmaxf(pa0, __shfl_xor(pa0, msk));
        pa1 = fmaxf(pa1, __shfl_xor(pa1, msk));
        pa2 = fmaxf(pa2, __shfl_xor(pa2, msk));
        pa3 = fmaxf(pa3, __shfl_xor(pa3, msk));
        pb0 = fmaxf(pb0, __shfl_xor(pb0, msk));
        pb1 = fmaxf(pb1, __shfl_xor(pb1, msk));
        pb2 = fmaxf(pb2, __shfl_xor(pb2, msk));
        pb3 = fmaxf(pb3, __shfl_xor(pb3, msk));
      }
      float na0 = fmaxf(ma0, pa0), na1 = fmaxf(ma1, pa1),
            na2 = fmaxf(ma2, pa2), na3 = fmaxf(ma3, pa3);
      float nb0 = fmaxf(mb0, pb0), nb1 = fmaxf(mb1, pb1),
            nb2 = fmaxf(mb2, pb2), nb3 = fmaxf(mb3, pb3);
      float sa0 = __expf(ma0 - na0), sa1 = __expf(ma1 - na1),
            sa2 = __expf(ma2 - na2), sa3 = __expf(ma3 - na3);
      float sb0 = __expf(mb0 - nb0), sb1 = __expf(mb1 - nb1),
            sb2 = __expf(mb2 - nb2), sb3 = __expf(mb3 - nb3);
      ma0 = na0; ma1 = na1; ma2 = na2; ma3 = na3;
      mb0 = nb0; mb1 = nb1; mb2 = nb2; mb3 = nb3;
      accsA[0] *= sa0; accsA[1] *= sa1; accsA[2] *= sa2; accsA[3] *= sa3;
      accsB[0] *= sb0; accsB[1] *= sb1; accsB[2] *= sb2; accsB[3] *= sb3;
      if (lq == 0) {
        Sc[w][4*hq+0] = sa0; Sc[w][4*hq+1] = sa1;
        Sc[w][4*hq+2] = sa2; Sc[w][4*hq+3] = sa3;
        Sc[w][16+4*hq+0] = sb0; Sc[w][16+4*hq+1] = sb1;
        Sc[w][16+4*hq+2] = sb2; Sc[w][16+4*hq+3] = sb3;
      }
      f32x4 s4[4];
      #pragma unroll
      for (int blk = 0; blk < 4; ++blk)
        s4[blk] = *(const f32x4*)&Sc[w][8*blk + 4*h2];
      #pragma unroll
      for (int fb = 0; fb < 8; ++fb)
        #pragma unroll
        for (int r = 0; r < 16; ++r)
          acc32[fb][r] *= s4[r>>2][r&3];
    }

    // P = exp(S - m) packed-interleaved f16: u32 holds (p=lq, p=16+lq)
    {
      int q0 = hq * 4;
      *(unsigned*)&Pw[q0+0][lq*2] = pk_f16(__expf(s0a[0]-ma0), __expf(s1a[0]-ma0));
      *(unsigned*)&Pw[q0+1][lq*2] = pk_f16(__expf(s0a[1]-ma1), __expf(s1a[1]-ma1));
      *(unsigned*)&Pw[q0+2][lq*2] = pk_f16(__expf(s0a[2]-ma2), __expf(s1a[2]-ma2));
      *(unsigned*)&Pw[q0+3][lq*2] = pk_f16(__expf(s0a[3]-ma3), __expf(s1a[3]-ma3));
      *(unsigned*)&Pw[16+q0+0][lq*2] = pk_f16(__expf(s0b[0]-mb0), __expf(s1b[0]-mb0));
      *(unsigned*)&Pw[16+q0+1][lq*2] = pk_f16(__expf(s0b[1]-mb1), __expf(s1b[1]-mb1));
      *(unsigned*)&Pw[16+q0+2][lq*2] = pk_f16(__expf(s0b[2]-mb2), __expf(s1b[2]-mb2));
      *(unsigned*)&Pw[16+q0+3][lq*2] = pk_f16(__expf(s0b[3]-mb3), __expf(s1b[3]-mb3));
    }

    // row-sums via ones-MFMA (k-order irrelevant)
    f16x8 paA = ld_f8(&Pw[lq][hq*8]);
    f16x8 paB = ld_f8(&Pw[16+lq][hq*8]);
    accsA = mfma16h(paA, ONESH, accsA);
    accsB = mfma16h(paB, ONESH, accsB);

    // PV via mfma 32x32x16 f16: A = P rows (q=lane&31), B = swizzled V granules
    #pragma unroll
    for (int ph = 0; ph < 2; ++ph) {
      f16x8 pfrag = ld_f8(&Pw[ln][ph*16 + h2*8]);
      #pragma unroll
      for (int fb = 0; fb < 8; ++fb) {
        int f = fb*32 + ln;
        int swz = ((fb*4 + (ln>>3)) & 7) << 4;
        f16x8 vfrag = ld_f8(Vl + (ph*2 + h2)*4096 + ((f*16) ^ swz));
        acc32[fb] = mfma32h(pfrag, vfrag, acc32[fb]);
      }
    }

    __syncthreads();   // tile t+1 staged by all waves; buf cur free for t+2
    cur ^= 1;
  }

  // ---- epilogue: per-slice normalized output (f16) + (m, rowsum) ----
  if (lq == 0) {
    As[w][4*hq+0] = accsA[0]; As[w][4*hq+1] = accsA[1];
    As[w][4*hq+2] = accsA[2]; As[w][4*hq+3] = accsA[3];
    As[w][16+4*hq+0] = accsB[0]; As[w][16+4*hq+1] = accsB[1];
    As[w][16+4*hq+2] = accsB[2]; As[w][16+4*hq+3] = accsB[3];
  }
  float inv[16];
  #pragma unroll
  for (int blk = 0; blk < 4; ++blk) {
    f32x4 a4 = *(const f32x4*)&As[w][8*blk + 4*h2];
    inv[blk*4+0] = 1.0f / a4[0]; inv[blk*4+1] = 1.0f / a4[1];
    inv[blk*4+2] = 1.0f / a4[2]; inv[blk*4+3] = 1.0f / a4[3];
  }
  size_t sbase = (size_t)slice * 16384 + qa0;
  #pragma unroll
  for (int fb = 0; fb < 8; ++fb) {
    #pragma unroll
    for (int r = 0; r < 16; ++r) {
      int q = (r & 3) + 8*(r >> 2) + 4*h2;
      accP[(sbase + q) * 256 + fb*32 + ln] = (_Float16)(acc32[fb][r] * inv[r]);
    }
  }
  if (lq == 0) {
    pm[sbase + 4*hq + 0] = ma0; ps[sbase + 4*hq + 0] = accsA[0];
    pm[sbase + 4*hq + 1] = ma1; ps[sbase + 4*hq + 1] = accsA[1];
    pm[sbase + 4*hq + 2] = ma2; ps[sbase + 4*hq + 2] = accsA[2];
    pm[sbase + 4*hq + 3] = ma3; ps[sbase + 4*hq + 3] = accsA[3];
    pm[sbase + 16 + 4*hq + 0] = mb0; ps[sbase + 16 + 4*hq + 0] = accsB[0];
    pm[sbase + 16 + 4*hq + 1] = mb1; ps[sbase + 16 + 4*hq + 1] = accsB[1];
    pm[sbase + 16 + 4*hq + 2] = mb2; ps[sbase + 16 + 4*hq + 2] = accsB[2];
    pm[sbase + 16 + 4*hq + 3] = mb3; ps[sbase + 16 + 4*hq + 3] = accsB[3];
  }
}

// ---------------- combine the 4 pool-slice partials (pre-normalized) ----------------
__global__ __launch_bounds__(256) void k_comb(const _Float16* __restrict__ accP,
                                              const float* __restrict__ pm,
                                              const float* __restrict__ ps,
                                              unsigned short* __restrict__ agg){
  int q = blockIdx.x * 16 + (threadIdx.x >> 4);
  int f0 = (threadIdx.x & 15) * 16;
  float m0 = pm[q], m1 = pm[16384 + q], m2 = pm[2*16384 + q], m3 = pm[3*16384 + q];
  float M = fmaxf(fmaxf(m0, m1), fmaxf(m2, m3));
  float w0 = __expf(m0 - M) * ps[q];
  float w1 = __expf(m1 - M) * ps[16384 + q];
  float w2 = __expf(m2 - M) * ps[2*16384 + q];
  float w3 = __expf(m3 - M) * ps[3*16384 + q];
  float inv = 1.0f / (w0 + w1 + w2 + w3);
  w0 *= inv; w1 *= inv; w2 *= inv; w3 *= inv;
  const _Float16* a0 = accP + (size_t)q * 256 + f0;
  #pragma unroll
  for (int j = 0; j < 16; j += 8) {
    f16x8 v0 = *(const f16x8*)(a0 + j);
    f16x8 v1 = *(const f16x8*)(a0 + j + (size_t)16384*256);
    f16x8 v2 = *(const f16x8*)(a0 + j + (size_t)2*16384*256);
    f16x8 v3 = *(const f16x8*)(a0 + j + (size_t)3*16384*256);
    u16x8 o;
    #pragma unroll
    for (int k = 0; k < 8; ++k) {
      float s = w0*(float)v0[k] + w1*(float)v1[k] + w2*(float)v2[k] + w3*(float)v3[k];
      o[k] = f2bf(s);
    }
    *(u16x8*)(agg + (size_t)q * 256 + f0 + j) = o;
  }
}

// ---------------- output GEMM + gated residual ----------------
__global__ __launch_bounds__(256) void k_out(const float* __restrict__ x,
                                             const unsigned short* __restrict__ wo,
                                             const unsigned short* __restrict__ agg,
                                             const float* __restrict__ gammap,
                                             float* __restrict__ out){
  int w = threadIdx.x >> 6, lane = threadIdx.x & 63;
  int lq = lane & 15, hq = lane >> 4;
  int b = blockIdx.x;
  int lg = b & 63, cg = (b >> 6) & 7, n = b >> 9;
  const char* wb = (const char*)wo;
  const char* ab = (const char*)agg;
  f32x4 acc[4];
  #pragma unroll
  for (int i = 0; i < 4; ++i) acc[i] = {};
  int crow = cg*64 + w*16 + lq;
  #pragma unroll
  for (int kk = 0; kk < 8; ++kk) {
    bf16x8 a = ld_bf8(wb + (size_t)crow * 512 + kk*64 + hq*16);
    #pragma unroll
    for (int li = 0; li < 4; ++li) {
      bf16x8 bb = ld_bf8(ab + (size_t)(n*HWD + lg*64 + li*16 + lq) * 512 + kk*64 + hq*16);
      acc[li] = mfma16(a, bb, acc[li]);
    }
  }
  float g = gammap[0];
  #pragma unroll
  for (int li = 0; li < 4; ++li) {
    #pragma unroll
    for (int r = 0; r < 4; ++r) {
      int c = cg*64 + w*16 + hq*4 + r;
      int l = lg*64 + li*16 + lq;
      size_t idx = ((size_t)(n*CHN + c)) * HWD + l;
      out[idx] = x[idx] + g * acc[li][r];
    }
  }
}

extern "C" void kernel_launch(void* const* d_in, const int* in_sizes, int n_in,
                              void* d_out, int out_size, void* d_ws, size_t ws_size,
                              hipStream_t stream) {
  const float* x     = (const float*)d_in[0];
  const float* wt    = (const float*)d_in[1];
  const float* wo    = (const float*)d_in[2];
  const float* pool  = (const float*)d_in[3];
  const float* gamma = (const float*)d_in[4];
  char* ws = (char*)d_ws;
  unsigned short* wt_b  = (unsigned short*)(ws + 0);         // 256 KB
  unsigned short* wo_b  = (unsigned short*)(ws + 262144);    // 256 KB
  _Float16*       poolV = (_Float16*)(ws + 524288);          // 4 MB (sigma-interleaved f16)
  unsigned short* poolT = (unsigned short*)(ws + 4718592);   // 4 MB (XOR-swizzled)
  unsigned short* Qb    = (unsigned short*)(ws + 8912896);   // 8 MB
  unsigned short* aggb  = (unsigned short*)(ws + 17301504);  // 8 MB
  unsigned short* xT    = (unsigned short*)(ws + 25690112);  // 16 MB (dead after k_theta)
  _Float16*       accP  = (_Float16*)(ws + 25690112);        // 32 MB (overlaps dead xT)
  float*          pm    = (float*)(ws + 59244544);           // 256 KB
  float*          ps    = (float*)(ws + 59506688);           // 256 KB
  float* out = (float*)d_out;

  k_cvt<<<dim3(128), dim3(256), 0, stream>>>(wt, wt_b, 32768);
  k_cvt<<<dim3(128), dim3(256), 0, stream>>>(wo, wo_b, 32768);
  k_poolV<<<dim3(1024), dim3(256), 0, stream>>>(pool, poolV);
  k_poolT<<<dim3(2048), dim3(256), 0, stream>>>(pool, poolT);
  k_xT<<<dim3(8192), dim3(256), 0, stream>>>(x, xT);
  k_theta<<<dim3(256), dim3(256), 0, stream>>>(xT, wt_b, Qb);
  k_attn<<<dim3(512), dim3(256), 0, stream>>>(Qb, poolT, poolV, accP, pm, ps);
  k_comb<<<dim3(1024), dim3(256), 0, stream>>>(accP, pm, ps, aggb);
  k_out<<<dim3(2048), dim3(256), 0, stream>>>(x, wo_b, aggb, gamma, out);
}

// Round 10
// 258.722 us; speedup vs baseline: 2.0512x; 1.4601x over previous
//
#include <hip/hip_runtime.h>

#define NB 4
#define CHN 512
#define HWD 4096
#define LTOT (NB*HWD)
#define FEAT_ 256
#define POOL_ 8192

typedef __attribute__((ext_vector_type(8))) __bf16 bf16x8;
typedef __attribute__((ext_vector_type(8))) unsigned short u16x8;
typedef __attribute__((ext_vector_type(8))) _Float16 f16x8;
typedef __attribute__((ext_vector_type(4))) float f32x4;
typedef __attribute__((ext_vector_type(16))) float f32x16;

static __device__ __forceinline__ unsigned short f2bf(float f){
  union { float f; unsigned u; } c; c.f = f;
  unsigned u = c.u;
  u += 0x7fffu + ((u >> 16) & 1u);   // round-to-nearest-even
  return (unsigned short)(u >> 16);
}

static __device__ __forceinline__ unsigned pk_f16(float lo, float hi){
  auto r = __builtin_amdgcn_cvt_pkrtz(lo, hi);   // __fp16 ext_vector(2)
  return __builtin_bit_cast(unsigned, r);        // [15:0]=f16(lo), [31:16]=f16(hi)
}

static __device__ __forceinline__ f32x4 mfma16(bf16x8 a, bf16x8 b, f32x4 c){
  return __builtin_amdgcn_mfma_f32_16x16x32_bf16(a, b, c, 0, 0, 0);
}
static __device__ __forceinline__ f32x4 mfma16h(f16x8 a, f16x8 b, f32x4 c){
  return __builtin_amdgcn_mfma_f32_16x16x32_f16(a, b, c, 0, 0, 0);
}
static __device__ __forceinline__ f32x16 mfma32h(f16x8 a, f16x8 b, f32x16 c){
  return __builtin_amdgcn_mfma_f32_32x32x16_f16(a, b, c, 0, 0, 0);
}

static __device__ __forceinline__ bf16x8 ld_bf8(const void* p){
  u16x8 v = *(const u16x8*)p;
  return __builtin_bit_cast(bf16x8, v);
}
static __device__ __forceinline__ f16x8 ld_f8(const void* p){
  u16x8 v = *(const u16x8*)p;
  return __builtin_bit_cast(f16x8, v);
}

static __device__ __forceinline__ void gload16(const void* g, void* l){
  __builtin_amdgcn_global_load_lds((const __attribute__((address_space(1))) void*)g,
                                   (__attribute__((address_space(3))) void*)l, 16, 0, 0);
}

// ---------------- f32 -> bf16 convert (layout-preserving) ----------------
__global__ void k_cvt(const float* __restrict__ src, unsigned short* __restrict__ dst, int n4){
  int i = blockIdx.x * 256 + threadIdx.x;
  if (i < n4) {
    const float4 v = *(const float4*)(src + (size_t)i * 4);
    ushort4 o; o.x = f2bf(v.x); o.y = f2bf(v.y); o.z = f2bf(v.z); o.w = f2bf(v.w);
    *(ushort4*)(dst + (size_t)i * 4) = o;
  }
}

// ---------------- pool -> poolKF: fragment-major K (bf16) ----------------
// poolKF[t][kk][half][lane][8]: lane's 16B = K[p=t*32+half*16+(lane&15)]
//                                            [f=kk*32+(lane>>4)*8+j]
// Wave reads at (base + lane*16) are conflict-free; staging is linear.
__global__ __launch_bounds__(256) void k_poolKF(const float* __restrict__ pool,
                                                unsigned short* __restrict__ poolKF){
  int t = blockIdx.x >> 2;
  int tid = threadIdx.x;
  int kk = ((blockIdx.x & 3) << 1) | (tid >> 7);
  int half = (tid >> 6) & 1;
  int lane = tid & 63;
  int p = t*32 + half*16 + (lane & 15);
  int f0 = kk*32 + ((lane >> 4) & 3)*8;
  u16x8 o;
  #pragma unroll
  for (int j = 0; j < 8; ++j) o[j] = f2bf(pool[(size_t)(f0+j)*POOL_ + p]);
  *(u16x8*)((char*)poolKF + (size_t)t*16384 + (kk*2+half)*1024 + lane*16) = o;
}

// ---------------- pool -> poolVF: fragment-major V (f16, sigma-interleaved) --
// poolVF[t][ph][fb][lane][8]: lane's 16B = V[p=t*32+sig(ph*16+(lane>>5)*8+j)]
//                                           [f=fb*32+(lane&31)],
// sig(s) = (s>>1) + 16*(s&1)  (matches packed-P k-slot order).
__global__ __launch_bounds__(256) void k_poolVF(const float* __restrict__ pool,
                                                _Float16* __restrict__ poolVF){
  int t = blockIdx.x >> 2;
  int tid = threadIdx.x;
  int g = ((blockIdx.x & 3) << 2) | (tid >> 6);   // 0-15: ph=g>>3, fb=g&7
  int lane = tid & 63;
  int f = (g & 7)*32 + (lane & 31);
  int sb = ((g >> 3) << 4) + ((lane >> 5) << 3);
  f16x8 o;
  #pragma unroll
  for (int j = 0; j < 8; ++j) {
    int s = sb + j;
    int po = (s >> 1) + ((s & 1) << 4);
    o[j] = (_Float16)pool[(size_t)f*POOL_ + t*32 + po];
  }
  *(f16x8*)((char*)poolVF + (size_t)t*16384 + g*1024 + lane*16) = o;
}

// ---------------- x [4][512][4096] f32 -> xT [4][4096][512] bf16 ----------------
__global__ __launch_bounds__(256) void k_xT(const float* __restrict__ x,
                                            unsigned short* __restrict__ xT){
  __shared__ float tile[32][33];
  int b = blockIdx.x;
  int lt = b & 127; int ct = (b >> 7) & 15; int n = b >> 11;
  int t = threadIdx.x;
  int fi = t >> 3, j = (t & 7) * 4;
  const float4 v = *(const float4*)(x + ((size_t)(n*CHN + ct*32 + fi)) * HWD + lt*32 + j);
  tile[fi][j+0] = v.x; tile[fi][j+1] = v.y; tile[fi][j+2] = v.z; tile[fi][j+3] = v.w;
  __syncthreads();
  int pi = t >> 3, fj = (t & 7) * 4;
  ushort4 o;
  o.x = f2bf(tile[fj+0][pi]); o.y = f2bf(tile[fj+1][pi]);
  o.z = f2bf(tile[fj+2][pi]); o.w = f2bf(tile[fj+3][pi]);
  *(ushort4*)((char*)xT + ((size_t)(n*HWD + lt*32 + pi)) * 1024 + (ct*32 + fj) * 2) = o;
}

// ---------------- theta GEMM: Q[l][f] = sum_c xT[l][c] * wt[f][c] ----------------
__global__ __launch_bounds__(256) void k_theta(const unsigned short* __restrict__ xT,
                                               const unsigned short* __restrict__ wt,
                                               unsigned short* __restrict__ Q){
  int w = threadIdx.x >> 6, lane = threadIdx.x & 63;
  int lq = lane & 15, hq = lane >> 4;
  int lbase = blockIdx.x * 64 + w * 16;
  const char* xb = (const char*)xT;
  const char* wb = (const char*)wt;
  f32x4 acc[16];
  #pragma unroll
  for (int i = 0; i < 16; ++i) acc[i] = {};
  #pragma unroll 2
  for (int kk = 0; kk < 16; ++kk) {
    bf16x8 a = ld_bf8(xb + (size_t)(lbase + lq) * 1024 + kk*64 + hq*16);
    #pragma unroll
    for (int fi = 0; fi < 16; ++fi) {
      bf16x8 bfr = ld_bf8(wb + (size_t)(fi*16 + lq) * 1024 + kk*64 + hq*16);
      acc[fi] = mfma16(a, bfr, acc[fi]);
    }
  }
  #pragma unroll
  for (int fi = 0; fi < 16; ++fi) {
    #pragma unroll
    for (int r = 0; r < 4; ++r) {
      int l = lbase + hq*4 + r;
      Q[(size_t)l * 256 + fi*16 + lq] = f2bf(acc[fi][r]);
    }
  }
}

// ---------------- fused flash attention over the concept pool ----------------
// Grid 512 = 128 q-blocks x 4 slices; block 256 thr = 4 waves x 32 q-rows.
// Verified 2-phase pipeline (R9, replay-stable): STAGE(t+1) -> compute(t) ->
// __syncthreads(). K/V double-buffered, FRAGMENT-MAJOR in LDS: every read is
// base + lane*16 + imm -> conflict-free, minimal addr VALU.
__global__ __launch_bounds__(256, 2) void k_attn(const unsigned short* __restrict__ Qg,
                                                 const unsigned short* __restrict__ poolKF,
                                                 const _Float16* __restrict__ poolVF,
                                                 _Float16* __restrict__ accP,
                                                 float* __restrict__ pm,
                                                 float* __restrict__ ps){
  __shared__ __attribute__((aligned(16))) unsigned short K_lds[2][32*256]; // 32 KB
  __shared__ __attribute__((aligned(16))) _Float16 V_lds[2][8192];         // 32 KB
  __shared__ __attribute__((aligned(16))) _Float16 P_lds[4][32][40];       // 10 KB
  __shared__ float Sc[4][32];
  __shared__ float As[4][32];

  int w = threadIdx.x >> 6, lane = threadIdx.x & 63;
  int lq = lane & 15, hq = lane >> 4;
  int ln = lane & 31, h2 = lane >> 5;
  int qblock = blockIdx.x & 127, slice = blockIdx.x >> 7;
  int qa0 = qblock * 128 + w * 32;

  const char* qp = (const char*)Qg;
  bf16x8 qfa[8], qfb[8];
  #pragma unroll
  for (int kk = 0; kk < 8; ++kk) {
    qfa[kk] = ld_bf8(qp + (size_t)(qa0 + lq) * 512 + kk*64 + hq*16);
    qfb[kk] = ld_bf8(qp + (size_t)(qa0 + 16 + lq) * 512 + kk*64 + hq*16);
  }

  f32x16 acc32[8];
  #pragma unroll
  for (int i = 0; i < 8; ++i) acc32[i] = {};
  f32x4 accsA = {}, accsB = {};
  float ma0 = -__builtin_inff(), ma1 = -__builtin_inff(),
        ma2 = -__builtin_inff(), ma3 = -__builtin_inff();
  float mb0 = -__builtin_inff(), mb1 = -__builtin_inff(),
        mb2 = -__builtin_inff(), mb3 = -__builtin_inff();
  u16x8 ov;
  #pragma unroll
  for (int i = 0; i < 8; ++i) ov[i] = 0x3C00;   // f16 1.0
  const f16x8 ONESH = __builtin_bit_cast(f16x8, ov);

  const char* ktb = (const char*)poolKF;
  const char* vnb = (const char*)poolVF;
  // 16 K-chunks + 16 V-chunks of 1KB per tile, 4+4 per wave.
  // LDS dst must stay wave-uniform (ck*1024); global src adds lane*16.
  int kds[4];
  #pragma unroll
  for (int i = 0; i < 4; ++i) kds[i] = (w*4 + i) * 1024;
  int lsrc = lane * 16;
  _Float16 (*Pw)[40] = P_lds[w];

  // prologue: stage tile 0 into buffer 0, full drain via __syncthreads
  {
    size_t tb = (size_t)(slice * 64) * 16384;
    #pragma unroll
    for (int i = 0; i < 4; ++i) {
      gload16(ktb + tb + kds[i] + lsrc, (char*)K_lds[0] + kds[i]);
      gload16(vnb + tb + kds[i] + lsrc, (char*)V_lds[0] + kds[i]);
    }
  }
  __syncthreads();

  int cur = 0;
  for (int t = 0; t < 64; ++t) {
    // STAGE(t+1) into buf cur^1 (last read at t-1, sealed by the barrier)
    if (t < 63) {
      size_t tb = (size_t)(slice*64 + t + 1) * 16384;
      #pragma unroll
      for (int i = 0; i < 4; ++i) {
        gload16(ktb + tb + kds[i] + lsrc, (char*)K_lds[cur^1] + kds[i]);
        gload16(vnb + tb + kds[i] + lsrc, (char*)V_lds[cur^1] + kds[i]);
      }
    }

    const char* Kb = (const char*)K_lds[cur] + lsrc;
    const char* Vb = (const char*)V_lds[cur] + lsrc;

    // S = Q @ K^T : two q-groups x 32 p (fragment-major K: base+imm reads)
    f32x4 s0a = {}, s1a = {}, s0b = {}, s1b = {};
    #pragma unroll
    for (int kk = 0; kk < 8; ++kk) {
      bf16x8 k0 = ld_bf8(Kb + kk*2048);
      bf16x8 k1 = ld_bf8(Kb + kk*2048 + 1024);
      s0a = mfma16(qfa[kk], k0, s0a);
      s1a = mfma16(qfa[kk], k1, s1a);
      s0b = mfma16(qfb[kk], k0, s0b);
      s1b = mfma16(qfb[kk], k1, s1b);
    }

    // defer-max online softmax: rescale only when max grows by > 4
    float pa0 = fmaxf(s0a[0], s1a[0]), pa1 = fmaxf(s0a[1], s1a[1]),
          pa2 = fmaxf(s0a[2], s1a[2]), pa3 = fmaxf(s0a[3], s1a[3]);
    float pb0 = fmaxf(s0b[0], s1b[0]), pb1 = fmaxf(s0b[1], s1b[1]),
          pb2 = fmaxf(s0b[2], s1b[2]), pb3 = fmaxf(s0b[3], s1b[3]);
    bool ex = (pa0 > ma0+4.f) | (pa1 > ma1+4.f) | (pa2 > ma2+4.f) | (pa3 > ma3+4.f) |
              (pb0 > mb0+4.f) | (pb1 > mb1+4.f) | (pb2 > mb2+4.f) | (pb3 > mb3+4.f);
    if (__any((int)ex)) {
      #pragma unroll
      for (int msk = 1; msk < 16; msk <<= 1) {
        pa0 = fmaxf(pa0, __shfl_xor(pa0, msk));
        pa1 = fmaxf(pa1, __shfl_xor(pa1, msk));
        pa2 = fmaxf(pa2, __shfl_xor(pa2, msk));
        pa3 = fmaxf(pa3, __shfl_xor(pa3, msk));
        pb0 = fmaxf(pb0, __shfl_xor(pb0, msk));
        pb1 = fmaxf(pb1, __shfl_xor(pb1, msk));
        pb2 = fmaxf(pb2, __shfl_xor(pb2, msk));
        pb3 = fmaxf(pb3, __shfl_xor(pb3, msk));
      }
      float na0 = fmaxf(ma0, pa0), na1 = fmaxf(ma1, pa1),
            na2 = fmaxf(ma2, pa2), na3 = fmaxf(ma3, pa3);
      float nb0 = fmaxf(mb0, pb0), nb1 = fmaxf(mb1, pb1),
            nb2 = fmaxf(mb2, pb2), nb3 = fmaxf(mb3, pb3);
      float sa0 = __expf(ma0 - na0), sa1 = __expf(ma1 - na1),
            sa2 = __expf(ma2 - na2), sa3 = __expf(ma3 - na3);
      float sb0 = __expf(mb0 - nb0), sb1 = __expf(mb1 - nb1),
            sb2 = __expf(mb2 - nb2), sb3 = __expf(mb3 - nb3);
      ma0 = na0; ma1 = na1; ma2 = na2; ma3 = na3;
      mb0 = nb0; mb1 = nb1; mb2 = nb2; mb3 = nb3;
      accsA[0] *= sa0; accsA[1] *= sa1; accsA[2] *= sa2; accsA[3] *= sa3;
      accsB[0] *= sb0; accsB[1] *= sb1; accsB[2] *= sb2; accsB[3] *= sb3;
      if (lq == 0) {
        Sc[w][4*hq+0] = sa0; Sc[w][4*hq+1] = sa1;
        Sc[w][4*hq+2] = sa2; Sc[w][4*hq+3] = sa3;
        Sc[w][16+4*hq+0] = sb0; Sc[w][16+4*hq+1] = sb1;
        Sc[w][16+4*hq+2] = sb2; Sc[w][16+4*hq+3] = sb3;
      }
      f32x4 s4[4];
      #pragma unroll
      for (int blk = 0; blk < 4; ++blk)
        s4[blk] = *(const f32x4*)&Sc[w][8*blk + 4*h2];
      #pragma unroll
      for (int fb = 0; fb < 8; ++fb)
        #pragma unroll
        for (int r = 0; r < 16; ++r)
          acc32[fb][r] *= s4[r>>2][r&3];
    }

    // P = exp(S - m) packed-interleaved f16: u32 holds (p=lq, p=16+lq)
    {
      int q0 = hq * 4;
      *(unsigned*)&Pw[q0+0][lq*2] = pk_f16(__expf(s0a[0]-ma0), __expf(s1a[0]-ma0));
      *(unsigned*)&Pw[q0+1][lq*2] = pk_f16(__expf(s0a[1]-ma1), __expf(s1a[1]-ma1));
      *(unsigned*)&Pw[q0+2][lq*2] = pk_f16(__expf(s0a[2]-ma2), __expf(s1a[2]-ma2));
      *(unsigned*)&Pw[q0+3][lq*2] = pk_f16(__expf(s0a[3]-ma3), __expf(s1a[3]-ma3));
      *(unsigned*)&Pw[16+q0+0][lq*2] = pk_f16(__expf(s0b[0]-mb0), __expf(s1b[0]-mb0));
      *(unsigned*)&Pw[16+q0+1][lq*2] = pk_f16(__expf(s0b[1]-mb1), __expf(s1b[1]-mb1));
      *(unsigned*)&Pw[16+q0+2][lq*2] = pk_f16(__expf(s0b[2]-mb2), __expf(s1b[2]-mb2));
      *(unsigned*)&Pw[16+q0+3][lq*2] = pk_f16(__expf(s0b[3]-mb3), __expf(s1b[3]-mb3));
    }

    // row-sums via ones-MFMA (k-order irrelevant)
    f16x8 paA = ld_f8(&Pw[lq][hq*8]);
    f16x8 paB = ld_f8(&Pw[16+lq][hq*8]);
    accsA = mfma16h(paA, ONESH, accsA);
    accsB = mfma16h(paB, ONESH, accsB);

    // PV via mfma 32x32x16 f16: A = P rows, B = fragment-major V (base+imm)
    #pragma unroll
    for (int ph = 0; ph < 2; ++ph) {
      f16x8 pfrag = ld_f8(&Pw[ln][ph*16 + h2*8]);
      #pragma unroll
      for (int fb = 0; fb < 8; ++fb) {
        f16x8 vfrag = ld_f8(Vb + (ph*8 + fb)*1024);
        acc32[fb] = mfma32h(pfrag, vfrag, acc32[fb]);
      }
    }

    __syncthreads();   // tile t+1 staged by all waves; buf cur free for t+2
    cur ^= 1;
  }

  // ---- epilogue: per-slice normalized output (f16) + (m, rowsum) ----
  if (lq == 0) {
    As[w][4*hq+0] = accsA[0]; As[w][4*hq+1] = accsA[1];
    As[w][4*hq+2] = accsA[2]; As[w][4*hq+3] = accsA[3];
    As[w][16+4*hq+0] = accsB[0]; As[w][16+4*hq+1] = accsB[1];
    As[w][16+4*hq+2] = accsB[2]; As[w][16+4*hq+3] = accsB[3];
  }
  float inv[16];
  #pragma unroll
  for (int blk = 0; blk < 4; ++blk) {
    f32x4 a4 = *(const f32x4*)&As[w][8*blk + 4*h2];
    inv[blk*4+0] = 1.0f / a4[0]; inv[blk*4+1] = 1.0f / a4[1];
    inv[blk*4+2] = 1.0f / a4[2]; inv[blk*4+3] = 1.0f / a4[3];
  }
  size_t sbase = (size_t)slice * 16384 + qa0;
  #pragma unroll
  for (int fb = 0; fb < 8; ++fb) {
    #pragma unroll
    for (int r = 0; r < 16; ++r) {
      int q = (r & 3) + 8*(r >> 2) + 4*h2;
      accP[(sbase + q) * 256 + fb*32 + ln] = (_Float16)(acc32[fb][r] * inv[r]);
    }
  }
  if (lq == 0) {
    pm[sbase + 4*hq + 0] = ma0; ps[sbase + 4*hq + 0] = accsA[0];
    pm[sbase + 4*hq + 1] = ma1; ps[sbase + 4*hq + 1] = accsA[1];
    pm[sbase + 4*hq + 2] = ma2; ps[sbase + 4*hq + 2] = accsA[2];
    pm[sbase + 4*hq + 3] = ma3; ps[sbase + 4*hq + 3] = accsA[3];
    pm[sbase + 16 + 4*hq + 0] = mb0; ps[sbase + 16 + 4*hq + 0] = accsB[0];
    pm[sbase + 16 + 4*hq + 1] = mb1; ps[sbase + 16 + 4*hq + 1] = accsB[1];
    pm[sbase + 16 + 4*hq + 2] = mb2; ps[sbase + 16 + 4*hq + 2] = accsB[2];
    pm[sbase + 16 + 4*hq + 3] = mb3; ps[sbase + 16 + 4*hq + 3] = accsB[3];
  }
}

// ---------------- combine the 4 pool-slice partials (pre-normalized) ----------------
__global__ __launch_bounds__(256) void k_comb(const _Float16* __restrict__ accP,
                                              const float* __restrict__ pm,
                                              const float* __restrict__ ps,
                                              unsigned short* __restrict__ agg){
  int q = blockIdx.x * 16 + (threadIdx.x >> 4);
  int f0 = (threadIdx.x & 15) * 16;
  float m0 = pm[q], m1 = pm[16384 + q], m2 = pm[2*16384 + q], m3 = pm[3*16384 + q];
  float M = fmaxf(fmaxf(m0, m1), fmaxf(m2, m3));
  float w0 = __expf(m0 - M) * ps[q];
  float w1 = __expf(m1 - M) * ps[16384 + q];
  float w2 = __expf(m2 - M) * ps[2*16384 + q];
  float w3 = __expf(m3 - M) * ps[3*16384 + q];
  float inv = 1.0f / (w0 + w1 + w2 + w3);
  w0 *= inv; w1 *= inv; w2 *= inv; w3 *= inv;
  const _Float16* a0 = accP + (size_t)q * 256 + f0;
  #pragma unroll
  for (int j = 0; j < 16; j += 8) {
    f16x8 v0 = *(const f16x8*)(a0 + j);
    f16x8 v1 = *(const f16x8*)(a0 + j + (size_t)16384*256);
    f16x8 v2 = *(const f16x8*)(a0 + j + (size_t)2*16384*256);
    f16x8 v3 = *(const f16x8*)(a0 + j + (size_t)3*16384*256);
    u16x8 o;
    #pragma unroll
    for (int k = 0; k < 8; ++k) {
      float s = w0*(float)v0[k] + w1*(float)v1[k] + w2*(float)v2[k] + w3*(float)v3[k];
      o[k] = f2bf(s);
    }
    *(u16x8*)(agg + (size_t)q * 256 + f0 + j) = o;
  }
}

// ---------------- output GEMM + gated residual ----------------
__global__ __launch_bounds__(256) void k_out(const float* __restrict__ x,
                                             const unsigned short* __restrict__ wo,
                                             const unsigned short* __restrict__ agg,
                                             const float* __restrict__ gammap,
                                             float* __restrict__ out){
  int w = threadIdx.x >> 6, lane = threadIdx.x & 63;
  int lq = lane & 15, hq = lane >> 4;
  int b = blockIdx.x;
  int lg = b & 63, cg = (b >> 6) & 7, n = b >> 9;
  const char* wb = (const char*)wo;
  const char* ab = (const char*)agg;
  f32x4 acc[4];
  #pragma unroll
  for (int i = 0; i < 4; ++i) acc[i] = {};
  int crow = cg*64 + w*16 + lq;
  #pragma unroll
  for (int kk = 0; kk < 8; ++kk) {
    bf16x8 a = ld_bf8(wb + (size_t)crow * 512 + kk*64 + hq*16);
    #pragma unroll
    for (int li = 0; li < 4; ++li) {
      bf16x8 bb = ld_bf8(ab + (size_t)(n*HWD + lg*64 + li*16 + lq) * 512 + kk*64 + hq*16);
      acc[li] = mfma16(a, bb, acc[li]);
    }
  }
  float g = gammap[0];
  #pragma unroll
  for (int li = 0; li < 4; ++li) {
    #pragma unroll
    for (int r = 0; r < 4; ++r) {
      int c = cg*64 + w*16 + hq*4 + r;
      int l = lg*64 + li*16 + lq;
      size_t idx = ((size_t)(n*CHN + c)) * HWD + l;
      out[idx] = x[idx] + g * acc[li][r];
    }
  }
}

extern "C" void kernel_launch(void* const* d_in, const int* in_sizes, int n_in,
                              void* d_out, int out_size, void* d_ws, size_t ws_size,
                              hipStream_t stream) {
  const float* x     = (const float*)d_in[0];
  const float* wt    = (const float*)d_in[1];
  const float* wo    = (const float*)d_in[2];
  const float* pool  = (const float*)d_in[3];
  const float* gamma = (const float*)d_in[4];
  char* ws = (char*)d_ws;
  unsigned short* wt_b  = (unsigned short*)(ws + 0);         // 256 KB
  unsigned short* wo_b  = (unsigned short*)(ws + 262144);    // 256 KB
  _Float16*       poolVF= (_Float16*)(ws + 524288);          // 4 MB (fragment-major f16)
  unsigned short* poolKF= (unsigned short*)(ws + 4718592);   // 4 MB (fragment-major bf16)
  unsigned short* Qb    = (unsigned short*)(ws + 8912896);   // 8 MB
  unsigned short* aggb  = (unsigned short*)(ws + 17301504);  // 8 MB
  unsigned short* xT    = (unsigned short*)(ws + 25690112);  // 16 MB (dead after k_theta)
  _Float16*       accP  = (_Float16*)(ws + 25690112);        // 32 MB (overlaps dead xT)
  float*          pm    = (float*)(ws + 59244544);           // 256 KB
  float*          ps    = (float*)(ws + 59506688);           // 256 KB
  float* out = (float*)d_out;

  k_cvt<<<dim3(128), dim3(256), 0, stream>>>(wt, wt_b, 32768);
  k_cvt<<<dim3(128), dim3(256), 0, stream>>>(wo, wo_b, 32768);
  k_poolVF<<<dim3(1024), dim3(256), 0, stream>>>(pool, poolVF);
  k_poolKF<<<dim3(1024), dim3(256), 0, stream>>>(pool, poolKF);
  k_xT<<<dim3(8192), dim3(256), 0, stream>>>(x, xT);
  k_theta<<<dim3(256), dim3(256), 0, stream>>>(xT, wt_b, Qb);
  k_attn<<<dim3(512), dim3(256), 0, stream>>>(Qb, poolKF, poolVF, accP, pm, ps);
  k_comb<<<dim3(1024), dim3(256), 0, stream>>>(accP, pm, ps, aggb);
  k_out<<<dim3(2048), dim3(256), 0, stream>>>(x, wo_b, aggb, gamma, out);
}

// Round 12
// 246.483 us; speedup vs baseline: 2.1531x; 1.0497x over previous
//
#include <hip/hip_runtime.h>

#define NB 4
#define CHN 512
#define HWD 4096
#define LTOT (NB*HWD)
#define FEAT_ 256
#define POOL_ 8192

typedef __attribute__((ext_vector_type(8))) __bf16 bf16x8;
typedef __attribute__((ext_vector_type(8))) unsigned short u16x8;
typedef __attribute__((ext_vector_type(8))) _Float16 f16x8;
typedef __attribute__((ext_vector_type(4))) unsigned u32x4;
typedef __attribute__((ext_vector_type(4))) float f32x4;
typedef __attribute__((ext_vector_type(16))) float f32x16;

static __device__ __forceinline__ float fexp2(float x){
  return __builtin_amdgcn_exp2f(x);   // raw v_exp_f32 (2^x)
}

static __device__ __forceinline__ unsigned short f2bf(float f){
  union { float f; unsigned u; } c; c.f = f;
  unsigned u = c.u;
  u += 0x7fffu + ((u >> 16) & 1u);   // round-to-nearest-even
  return (unsigned short)(u >> 16);
}

static __device__ __forceinline__ unsigned pk_f16(float lo, float hi){
  auto r = __builtin_amdgcn_cvt_pkrtz(lo, hi);   // __fp16 ext_vector(2)
  return __builtin_bit_cast(unsigned, r);        // [15:0]=f16(lo), [31:16]=f16(hi)
}

static __device__ __forceinline__ f32x4 mfma16(bf16x8 a, bf16x8 b, f32x4 c){
  return __builtin_amdgcn_mfma_f32_16x16x32_bf16(a, b, c, 0, 0, 0);
}
static __device__ __forceinline__ f32x16 mfma32b(bf16x8 a, bf16x8 b, f32x16 c){
  return __builtin_amdgcn_mfma_f32_32x32x16_bf16(a, b, c, 0, 0, 0);
}
static __device__ __forceinline__ f32x16 mfma32h(f16x8 a, f16x8 b, f32x16 c){
  return __builtin_amdgcn_mfma_f32_32x32x16_f16(a, b, c, 0, 0, 0);
}

static __device__ __forceinline__ bf16x8 ld_bf8(const void* p){
  u16x8 v = *(const u16x8*)p;
  return __builtin_bit_cast(bf16x8, v);
}
static __device__ __forceinline__ f16x8 ld_f8(const void* p){
  u16x8 v = *(const u16x8*)p;
  return __builtin_bit_cast(f16x8, v);
}

static __device__ __forceinline__ void gload16(const void* g, void* l){
  __builtin_amdgcn_global_load_lds((const __attribute__((address_space(1))) void*)g,
                                   (__attribute__((address_space(3))) void*)l, 16, 0, 0);
}

// ---------------- f32 -> bf16 convert (layout-preserving) ----------------
__global__ void k_cvt(const float* __restrict__ src, unsigned short* __restrict__ dst, int n4){
  int i = blockIdx.x * 256 + threadIdx.x;
  if (i < n4) {
    const float4 v = *(const float4*)(src + (size_t)i * 4);
    ushort4 o; o.x = f2bf(v.x); o.y = f2bf(v.y); o.z = f2bf(v.z); o.w = f2bf(v.w);
    *(ushort4*)(dst + (size_t)i * 4) = o;
  }
}

// ---------------- pool -> poolKF: A-fragment-major K (bf16, swapped QK^T) ----
// poolKF[t][kc][lane][8]: lane's 16B = K[p = t*32 + (lane&31)]
//                                       [f = kc*16 + (lane>>5)*8 + j]
__global__ __launch_bounds__(256) void k_poolKF(const float* __restrict__ pool,
                                                unsigned short* __restrict__ poolKF){
  int t = blockIdx.x >> 2;
  int tid = threadIdx.x;
  int kc = ((blockIdx.x & 3) << 2) | (tid >> 6);
  int lane = tid & 63;
  int p = t*32 + (lane & 31);
  int f0 = kc*16 + (lane >> 5)*8;
  u16x8 o;
  #pragma unroll
  for (int j = 0; j < 8; ++j) o[j] = f2bf(pool[(size_t)(f0+j)*POOL_ + p]);
  *(u16x8*)((char*)poolKF + (size_t)t*16384 + kc*1024 + lane*16) = o;
}

// ---------------- pool -> poolVF: B-fragment-major V (f16, reg-order sigma) --
// poolVF[t][g=ph*8+fb][lane][8]: lane's 16B = V[p][f=fb*32+(lane&31)] with
// p = t*32 + (j&3) + 8*(j>>2) + 4*(lane>>5) + 16*ph   (matches P-reg order)
__global__ __launch_bounds__(256) void k_poolVF(const float* __restrict__ pool,
                                                _Float16* __restrict__ poolVF){
  int t = blockIdx.x >> 2;
  int tid = threadIdx.x;
  int g = ((blockIdx.x & 3) << 2) | (tid >> 6);   // 0-15: ph=g>>3, fb=g&7
  int lane = tid & 63;
  int f = (g & 7)*32 + (lane & 31);
  int ph = g >> 3, h2 = lane >> 5;
  f16x8 o;
  #pragma unroll
  for (int j = 0; j < 8; ++j) {
    int po = (j & 3) + 8*(j >> 2) + 4*h2 + 16*ph;
    o[j] = (_Float16)pool[(size_t)f*POOL_ + t*32 + po];
  }
  *(f16x8*)((char*)poolVF + (size_t)t*16384 + g*1024 + lane*16) = o;
}

// ---------------- x [4][512][4096] f32 -> xT [4][4096][512] bf16 ----------------
__global__ __launch_bounds__(256) void k_xT(const float* __restrict__ x,
                                            unsigned short* __restrict__ xT){
  __shared__ float tile[32][33];
  int b = blockIdx.x;
  int lt = b & 127; int ct = (b >> 7) & 15; int n = b >> 11;
  int t = threadIdx.x;
  int fi = t >> 3, j = (t & 7) * 4;
  const float4 v = *(const float4*)(x + ((size_t)(n*CHN + ct*32 + fi)) * HWD + lt*32 + j);
  tile[fi][j+0] = v.x; tile[fi][j+1] = v.y; tile[fi][j+2] = v.z; tile[fi][j+3] = v.w;
  __syncthreads();
  int pi = t >> 3, fj = (t & 7) * 4;
  ushort4 o;
  o.x = f2bf(tile[fj+0][pi]); o.y = f2bf(tile[fj+1][pi]);
  o.z = f2bf(tile[fj+2][pi]); o.w = f2bf(tile[fj+3][pi]);
  *(ushort4*)((char*)xT + ((size_t)(n*HWD + lt*32 + pi)) * 1024 + (ct*32 + fj) * 2) = o;
}

// ---------------- theta GEMM: Q[l][f] = log2e * sum_c xT[l][c] * wt[f][c] ----
// (log2e pre-scale so k_attn softmax runs in exp2 domain)
__global__ __launch_bounds__(256) void k_theta(const unsigned short* __restrict__ xT,
                                               const unsigned short* __restrict__ wt,
                                               unsigned short* __restrict__ Q){
  int w = threadIdx.x >> 6, lane = threadIdx.x & 63;
  int lq = lane & 15, hq = lane >> 4;
  int lbase = blockIdx.x * 64 + w * 16;
  const char* xb = (const char*)xT;
  const char* wb = (const char*)wt;
  f32x4 acc[16];
  #pragma unroll
  for (int i = 0; i < 16; ++i) acc[i] = {};
  #pragma unroll 2
  for (int kk = 0; kk < 16; ++kk) {
    bf16x8 a = ld_bf8(xb + (size_t)(lbase + lq) * 1024 + kk*64 + hq*16);
    #pragma unroll
    for (int fi = 0; fi < 16; ++fi) {
      bf16x8 bfr = ld_bf8(wb + (size_t)(fi*16 + lq) * 1024 + kk*64 + hq*16);
      acc[fi] = mfma16(a, bfr, acc[fi]);
    }
  }
  #pragma unroll
  for (int fi = 0; fi < 16; ++fi) {
    #pragma unroll
    for (int r = 0; r < 4; ++r) {
      int l = lbase + hq*4 + r;
      Q[(size_t)l * 256 + fi*16 + lq] = f2bf(acc[fi][r] * 1.44269504f);
    }
  }
}

// ---------------- fused flash attention over the concept pool ----------------
// Grid 512 = 128 q-blocks x 4 slices; block 256 thr = 4 waves x 32 q-rows.
// 2-phase pipeline (R10, replay-stable). SWAPPED QK^T: S^T = mfma32(K, Q)
// puts each q's full 32-p row lane-local (q = lane&31) -> softmax is in-lane
// fmax chain + one shfl_xor(32); P packs via cvt_pkrtz straight into the PV
// A-fragment (poolVF's sigma matches reg order). No P LDS round-trip.
__global__ __launch_bounds__(256, 2) void k_attn(const unsigned short* __restrict__ Qg,
                                                 const unsigned short* __restrict__ poolKF,
                                                 const _Float16* __restrict__ poolVF,
                                                 _Float16* __restrict__ accP,
                                                 float* __restrict__ pm,
                                                 float* __restrict__ ps){
  __shared__ __attribute__((aligned(16))) unsigned short K_lds[2][32*256]; // 32 KB
  __shared__ __attribute__((aligned(16))) _Float16 V_lds[2][8192];         // 32 KB
  __shared__ float Sc[4][32];
  __shared__ float As[4][32];

  int w = threadIdx.x >> 6, lane = threadIdx.x & 63;
  int ln = lane & 31, h2 = lane >> 5;
  int qblock = blockIdx.x & 127, slice = blockIdx.x >> 7;
  int qa0 = qblock * 128 + w * 32;

  // Q as B-fragments for swapped QK^T: col=q=ln, k=(h2)*8+j per 16-k chunk
  const char* qp = (const char*)Qg;
  bf16x8 qf[16];
  #pragma unroll
  for (int kc = 0; kc < 16; ++kc)
    qf[kc] = ld_bf8(qp + (size_t)(qa0 + ln) * 512 + kc*32 + h2*16);

  f32x16 acc32[8];
  #pragma unroll
  for (int i = 0; i < 8; ++i) acc32[i] = {};
  float accs = 0.0f;                       // running rowsum for q = ln
  float m = -__builtin_inff();             // running max (log2 domain), q = ln

  const char* ktb = (const char*)poolKF;
  const char* vnb = (const char*)poolVF;
  int kds[4];
  #pragma unroll
  for (int i = 0; i < 4; ++i) kds[i] = (w*4 + i) * 1024;
  int lsrc = lane * 16;

  // prologue: stage tile 0 into buffer 0
  {
    size_t tb = (size_t)(slice * 64) * 16384;
    #pragma unroll
    for (int i = 0; i < 4; ++i) {
      gload16(ktb + tb + kds[i] + lsrc, (char*)K_lds[0] + kds[i]);
      gload16(vnb + tb + kds[i] + lsrc, (char*)V_lds[0] + kds[i]);
    }
  }
  __syncthreads();

  int cur = 0;
  for (int t = 0; t < 64; ++t) {
    if (t < 63) {
      size_t tb = (size_t)(slice*64 + t + 1) * 16384;
      #pragma unroll
      for (int i = 0; i < 4; ++i) {
        gload16(ktb + tb + kds[i] + lsrc, (char*)K_lds[cur^1] + kds[i]);
        gload16(vnb + tb + kds[i] + lsrc, (char*)V_lds[cur^1] + kds[i]);
      }
    }

    const char* Kb = (const char*)K_lds[cur] + lsrc;
    const char* Vb = (const char*)V_lds[cur] + lsrc;

    // S^T = K @ Q^T via mfma32 (A=K rows=p, B=Q cols=q): lane ln holds
    // S[p=(r&3)+8*(r>>2)+4*h2][q=ln] in regs r=0..15. Two interleaved chains.
    f32x16 Sa = {}, Sb = {};
    #pragma unroll
    for (int kc = 0; kc < 8; ++kc) {
      bf16x8 k0 = ld_bf8(Kb + (2*kc)*1024);
      bf16x8 k1 = ld_bf8(Kb + (2*kc+1)*1024);
      Sa = mfma32b(k0, qf[2*kc], Sa);
      Sb = mfma32b(k1, qf[2*kc+1], Sb);
    }
    float S[16];
    #pragma unroll
    for (int r = 0; r < 16; ++r) S[r] = Sa[r] + Sb[r];

    // lane-local softmax (q = ln): in-lane max over 16 + cross-half swap
    float px = S[0];
    #pragma unroll
    for (int r = 1; r < 16; ++r) px = fmaxf(px, S[r]);
    px = fmaxf(px, __shfl_xor(px, 32));

    // defer-max: rescale only when max grows by > 5.5 (log2 units)
    if (__any((int)(px > m + 5.5f))) {
      float mn = fmaxf(m, px);
      float sc = fexp2(m - mn);
      m = mn;
      accs *= sc;
      if (lane < 32) Sc[w][lane] = sc;   // broadcast per-q scale to all lanes
      f32x4 s4[4];
      #pragma unroll
      for (int blk = 0; blk < 4; ++blk)
        s4[blk] = *(const f32x4*)&Sc[w][8*blk + 4*h2];
      #pragma unroll
      for (int fb = 0; fb < 8; ++fb)
        #pragma unroll
        for (int r = 0; r < 16; ++r)
          acc32[fb][r] *= s4[r>>2][r&3];
    }

    // P = exp2(S - m) in-register + rowsum; pack into PV A-fragments
    float Pr[16];
    #pragma unroll
    for (int r = 0; r < 16; ++r) Pr[r] = fexp2(S[r] - m);
    float sum = (((Pr[0]+Pr[1])+(Pr[2]+Pr[3])) + ((Pr[4]+Pr[5])+(Pr[6]+Pr[7])))
              + (((Pr[8]+Pr[9])+(Pr[10]+Pr[11])) + ((Pr[12]+Pr[13])+(Pr[14]+Pr[15])));
    sum += __shfl_xor(sum, 32);
    accs += sum;
    u32x4 w0, w1;
    #pragma unroll
    for (int j = 0; j < 4; ++j) {
      w0[j] = pk_f16(Pr[2*j],   Pr[2*j+1]);
      w1[j] = pk_f16(Pr[8+2*j], Pr[8+2*j+1]);
    }
    f16x8 pa0 = __builtin_bit_cast(f16x8, w0);
    f16x8 pa1 = __builtin_bit_cast(f16x8, w1);

    // PV via mfma32h: A = packed P (row=q=ln, k per poolVF sigma), B = V frags
    #pragma unroll
    for (int fb = 0; fb < 8; ++fb) {
      f16x8 v0 = ld_f8(Vb + fb*1024);
      acc32[fb] = mfma32h(pa0, v0, acc32[fb]);
    }
    #pragma unroll
    for (int fb = 0; fb < 8; ++fb) {
      f16x8 v1 = ld_f8(Vb + (8 + fb)*1024);
      acc32[fb] = mfma32h(pa1, v1, acc32[fb]);
    }

    __syncthreads();   // tile t+1 staged by all waves; buf cur free for t+2
    cur ^= 1;
  }

  // ---- epilogue: per-slice normalized output (f16) + (m, rowsum) ----
  if (lane < 32) As[w][lane] = accs;
  float inv[16];
  #pragma unroll
  for (int blk = 0; blk < 4; ++blk) {
    f32x4 a4 = *(const f32x4*)&As[w][8*blk + 4*h2];
    inv[blk*4+0] = 1.0f / a4[0]; inv[blk*4+1] = 1.0f / a4[1];
    inv[blk*4+2] = 1.0f / a4[2]; inv[blk*4+3] = 1.0f / a4[3];
  }
  size_t sbase = (size_t)slice * 16384 + qa0;
  #pragma unroll
  for (int fb = 0; fb < 8; ++fb) {
    #pragma unroll
    for (int r = 0; r < 16; ++r) {
      int q = (r & 3) + 8*(r >> 2) + 4*h2;
      accP[(sbase + q) * 256 + fb*32 + ln] = (_Float16)(acc32[fb][r] * inv[r]);
    }
  }
  if (lane < 32) {            // per-q scalars live at lane q
    pm[sbase + lane] = m;     // log2-domain running max
    ps[sbase + lane] = accs;  // rowsum
  }
}

// ---------------- combine the 4 pool-slice partials (pre-normalized, log2 m) --
__global__ __launch_bounds__(256) void k_comb(const _Float16* __restrict__ accP,
                                              const float* __restrict__ pm,
                                              const float* __restrict__ ps,
                                              unsigned short* __restrict__ agg){
  int q = blockIdx.x * 16 + (threadIdx.x >> 4);
  int f0 = (threadIdx.x & 15) * 16;
  float m0 = pm[q], m1 = pm[16384 + q], m2 = pm[2*16384 + q], m3 = pm[3*16384 + q];
  float M = fmaxf(fmaxf(m0, m1), fmaxf(m2, m3));
  float w0 = fexp2(m0 - M) * ps[q];
  float w1 = fexp2(m1 - M) * ps[16384 + q];
  float w2 = fexp2(m2 - M) * ps[2*16384 + q];
  float w3 = fexp2(m3 - M) * ps[3*16384 + q];
  float inv = 1.0f / (w0 + w1 + w2 + w3);
  w0 *= inv; w1 *= inv; w2 *= inv; w3 *= inv;
  const _Float16* a0 = accP + (size_t)q * 256 + f0;
  #pragma unroll
  for (int j = 0; j < 16; j += 8) {
    f16x8 v0 = *(const f16x8*)(a0 + j);
    f16x8 v1 = *(const f16x8*)(a0 + j + (size_t)16384*256);
    f16x8 v2 = *(const f16x8*)(a0 + j + (size_t)2*16384*256);
    f16x8 v3 = *(const f16x8*)(a0 + j + (size_t)3*16384*256);
    u16x8 o;
    #pragma unroll
    for (int k = 0; k < 8; ++k) {
      float s = w0*(float)v0[k] + w1*(float)v1[k] + w2*(float)v2[k] + w3*(float)v3[k];
      o[k] = f2bf(s);
    }
    *(u16x8*)(agg + (size_t)q * 256 + f0 + j) = o;
  }
}

// ---------------- output GEMM + gated residual ----------------
__global__ __launch_bounds__(256) void k_out(const float* __restrict__ x,
                                             const unsigned short* __restrict__ wo,
                                             const unsigned short* __restrict__ agg,
                                             const float* __restrict__ gammap,
                                             float* __restrict__ out){
  int w = threadIdx.x >> 6, lane = threadIdx.x & 63;
  int lq = lane & 15, hq = lane >> 4;
  int b = blockIdx.x;
  int lg = b & 63, cg = (b >> 6) & 7, n = b >> 9;
  const char* wb = (const char*)wo;
  const char* ab = (const char*)agg;
  f32x4 acc[4];
  #pragma unroll
  for (int i = 0; i < 4; ++i) acc[i] = {};
  int crow = cg*64 + w*16 + lq;
  #pragma unroll
  for (int kk = 0; kk < 8; ++kk) {
    bf16x8 a = ld_bf8(wb + (size_t)crow * 512 + kk*64 + hq*16);
    #pragma unroll
    for (int li = 0; li < 4; ++li) {
      bf16x8 bb = ld_bf8(ab + (size_t)(n*HWD + lg*64 + li*16 + lq) * 512 + kk*64 + hq*16);
      acc[li] = mfma16(a, bb, acc[li]);
    }
  }
  float g = gammap[0];
  #pragma unroll
  for (int li = 0; li < 4; ++li) {
    #pragma unroll
    for (int r = 0; r < 4; ++r) {
      int c = cg*64 + w*16 + hq*4 + r;
      int l = lg*64 + li*16 + lq;
      size_t idx = ((size_t)(n*CHN + c)) * HWD + l;
      out[idx] = x[idx] + g * acc[li][r];
    }
  }
}

extern "C" void kernel_launch(void* const* d_in, const int* in_sizes, int n_in,
                              void* d_out, int out_size, void* d_ws, size_t ws_size,
                              hipStream_t stream) {
  const float* x     = (const float*)d_in[0];
  const float* wt    = (const float*)d_in[1];
  const float* wo    = (const float*)d_in[2];
  const float* pool  = (const float*)d_in[3];
  const float* gamma = (const float*)d_in[4];
  char* ws = (char*)d_ws;
  unsigned short* wt_b  = (unsigned short*)(ws + 0);         // 256 KB
  unsigned short* wo_b  = (unsigned short*)(ws + 262144);    // 256 KB
  _Float16*       poolVF= (_Float16*)(ws + 524288);          // 4 MB (fragment-major f16)
  unsigned short* poolKF= (unsigned short*)(ws + 4718592);   // 4 MB (fragment-major bf16)
  unsigned short* Qb    = (unsigned short*)(ws + 8912896);   // 8 MB
  unsigned short* aggb  = (unsigned short*)(ws + 17301504);  // 8 MB
  unsigned short* xT    = (unsigned short*)(ws + 25690112);  // 16 MB (dead after k_theta)
  _Float16*       accP  = (_Float16*)(ws + 25690112);        // 32 MB (overlaps dead xT)
  float*          pm    = (float*)(ws + 59244544);           // 256 KB
  float*          ps    = (float*)(ws + 59506688);           // 256 KB
  float* out = (float*)d_out;

  k_cvt<<<dim3(128), dim3(256), 0, stream>>>(wt, wt_b, 32768);
  k_cvt<<<dim3(128), dim3(256), 0, stream>>>(wo, wo_b, 32768);
  k_poolVF<<<dim3(1024), dim3(256), 0, stream>>>(pool, poolVF);
  k_poolKF<<<dim3(1024), dim3(256), 0, stream>>>(pool, poolKF);
  k_xT<<<dim3(8192), dim3(256), 0, stream>>>(x, xT);
  k_theta<<<dim3(256), dim3(256), 0, stream>>>(xT, wt_b, Qb);
  k_attn<<<dim3(512), dim3(256), 0, stream>>>(Qb, poolKF, poolVF, accP, pm, ps);
  k_comb<<<dim3(1024), dim3(256), 0, stream>>>(accP, pm, ps, aggb);
  k_out<<<dim3(2048), dim3(256), 0, stream>>>(x, wo_b, aggb, gamma, out);
}